// Round 4
// baseline (87585.693 us; speedup 1.0000x reference)
//
#include <hip/hip_runtime.h>

#define B_   128
#define L_   256
#define CIN  512
#define H_   256
#define T_   501
#define E_   30

typedef short short8 __attribute__((ext_vector_type(8)));
typedef float f32x4  __attribute__((ext_vector_type(4)));
typedef _Float16 f16;

__device__ __forceinline__ float bf2f(unsigned short s){ union{unsigned int i;float f;}v; v.i=((unsigned int)s)<<16; return v.f; }
__device__ __forceinline__ unsigned short f2bf(float f){
  union{float f;unsigned int i;}v; v.f=f;
  unsigned int x=v.i;
  return (unsigned short)((x + 0x7fffu + ((x>>16)&1u)) >> 16);
}
__device__ __forceinline__ float fast_tanh(float x){
  float t = __expf(2.f*x);
  return 1.f - 2.f*__builtin_amdgcn_rcpf(t + 1.f);
}
__device__ __forceinline__ float fast_sigm(float x){
  return __builtin_amdgcn_rcpf(1.f + __expf(-x));
}
// fp16-weight * fp32 fma with fp32 accumulate (targets v_fma_mix_f32)
__device__ __forceinline__ float fmam(f16 w, float h, float acc){ return fmaf((float)w, h, acc); }

// ---------------- workspace layout (bytes) ----------------
#define OFF_PROJ ((size_t)0)                                   // proj [B][256 l][256 h] f16 : 16,777,216
#define OFF_G    (OFF_PROJ + (size_t)B_*256*256*2)             // G2 [B][32 lt][768 c][8 li] f16 : 50,331,648
#define OFF_WCTH (OFF_G    + (size_t)B_*32*768*8*2)            // WcatT_hi [1024][512] bf16 : 1,048,576
#define OFF_WCTL (OFF_WCTH + (size_t)1024*512*2)               // WcatT_lo
#define OFF_WREC (OFF_WCTL + (size_t)1024*512*2)               // Wrec2 [32 jt][1024 c][8 ji] f16 : 524,288
#define OFF_WOUT (OFF_WREC + (size_t)32*1024*8*2)              // WoutT [64 o][256 j] f16 : 32,768
#define OFF_WIHE (OFF_WOUT + (size_t)64*256*2)                 // WiheT [30][768] f32 : 92,160
#define OFF_LC   (OFF_WIHE + (size_t)30*768*4)                 // LC [B][T][4] f32 : 1,026,048

// ---------------- weight repack ----------------
__global__ __launch_bounds__(256) void build_weights(
    const float* __restrict__ W_i2h, const float* __restrict__ W_h2h,
    const float* __restrict__ W_ih,  const float* __restrict__ W_hh,
    const float* __restrict__ W_gen, const float* __restrict__ W_locgen,
    unsigned short* __restrict__ WcatT_hi, unsigned short* __restrict__ WcatT_lo,
    f16* __restrict__ Wrec2, f16* __restrict__ WoutT, float* __restrict__ WiheT)
{
  int idx = blockIdx.x*256 + threadIdx.x;
  if (idx < 524288) {                       // WcatT[n][c]: n<256 -> W_i2h row n; else W_ih row n-256 (cols 0..511)
    int n = idx >> 9, c = idx & 511;
    float v = (n < 256) ? W_i2h[n*512 + c] : W_ih[(n-256)*542 + c];
    unsigned short hi = f2bf(v);
    WcatT_hi[idx] = hi;
    WcatT_lo[idx] = f2bf(v - bf2f(hi));
    return;
  }
  idx -= 524288;
  if (idx < 262144) {                       // Wrec2[jt][col][ji] = W[col][j], j = jt*8+ji
    int ji = idx & 7, col = (idx >> 3) & 1023, jt = idx >> 13;
    int j = jt*8 + ji;
    float v = (col < 256) ? W_h2h[col*256 + j] : W_hh[(col-256)*256 + j];
    Wrec2[idx] = (f16)v; return;
  }
  idx -= 262144;
  if (idx < 16384) {                        // WoutT[o][j]: o<30 logits, o in [32,36) loc-hidden, else 0
    int o = idx >> 8, j = idx & 255;
    float v = 0.f;
    if (o < 30) v = W_gen[o*256 + j];
    else if (o >= 32 && o < 36) v = W_locgen[(o-32)*768 + j];
    WoutT[idx] = (f16)v; return;
  }
  idx -= 16384;
  if (idx < 23040) {                        // WiheT[e][k] = W_ih[k][512+e]
    int e = idx / 768, k = idx - e*768;
    WiheT[idx] = W_ih[k*542 + 512 + e];
  }
}

// ---------------- precompute GEMM, 3-pass split-bf16 (~fp32 exact): C[b] = fea[b] @ Wcat ----------------
__global__ __launch_bounds__(256) void gemm_kernel(
    const float* __restrict__ fea,
    const unsigned short* __restrict__ WcatT_hi,   // [1024][512] bf16
    const unsigned short* __restrict__ WcatT_lo,
    f16* __restrict__ ProjH,                       // [B][256][256]
    f16* __restrict__ GH)                          // [B][32][768][8]
{
  const int b = blockIdx.y;
  const int mt = blockIdx.x & 1, nt = blockIdx.x >> 1;
  const int m0 = mt*128, n0 = nt*128;
  const int tid = threadIdx.x;
  const int w = tid >> 6, lane = tid & 63;
  const int wm = w >> 1, wn = w & 1;
  const int quad = lane >> 4, l16 = lane & 15;

  __shared__ unsigned short AsH[128][40];
  __shared__ unsigned short AsL[128][40];
  __shared__ unsigned short BsH[128][40];
  __shared__ unsigned short BsL[128][40];

  f32x4 acc[4][4];
#pragma unroll
  for (int i=0;i<4;++i)
#pragma unroll
    for (int j=0;j<4;++j) acc[i][j] = (f32x4){0.f,0.f,0.f,0.f};

  const int r = tid >> 1, hf = tid & 1;

  for (int kt = 0; kt < 16; ++kt) {
    const int c0 = kt*32;
    {
      const float* src = fea + ((size_t)b*L_ + (m0+r))*CIN + c0 + hf*16;
      union { unsigned short s[8]; uint4 v; } h0, h1, l0, l1;
#pragma unroll
      for (int q4 = 0; q4 < 4; ++q4) {
        float4 f = ((const float4*)src)[q4];
        unsigned short hx = f2bf(f.x), hy = f2bf(f.y), hz = f2bf(f.z), hw = f2bf(f.w);
        unsigned short lx = f2bf(f.x - bf2f(hx)), ly = f2bf(f.y - bf2f(hy));
        unsigned short lz = f2bf(f.z - bf2f(hz)), lw = f2bf(f.w - bf2f(hw));
        if (q4 < 2) { int o = q4*4;
          h0.s[o]=hx; h0.s[o+1]=hy; h0.s[o+2]=hz; h0.s[o+3]=hw;
          l0.s[o]=lx; l0.s[o+1]=ly; l0.s[o+2]=lz; l0.s[o+3]=lw;
        } else { int o = (q4-2)*4;
          h1.s[o]=hx; h1.s[o+1]=hy; h1.s[o+2]=hz; h1.s[o+3]=hw;
          l1.s[o]=lx; l1.s[o+1]=ly; l1.s[o+2]=lz; l1.s[o+3]=lw;
        }
      }
      *(uint4*)&AsH[r][hf*16]   = h0.v;
      *(uint4*)&AsH[r][hf*16+8] = h1.v;
      *(uint4*)&AsL[r][hf*16]   = l0.v;
      *(uint4*)&AsL[r][hf*16+8] = l1.v;
      const size_t bo = ((size_t)(n0+r))*CIN + c0 + hf*16;
      uint4 bh0 = ((const uint4*)(WcatT_hi + bo))[0];
      uint4 bh1 = ((const uint4*)(WcatT_hi + bo))[1];
      uint4 bl0 = ((const uint4*)(WcatT_lo + bo))[0];
      uint4 bl1 = ((const uint4*)(WcatT_lo + bo))[1];
      *(uint4*)&BsH[r][hf*16]   = bh0;
      *(uint4*)&BsH[r][hf*16+8] = bh1;
      *(uint4*)&BsL[r][hf*16]   = bl0;
      *(uint4*)&BsL[r][hf*16+8] = bl1;
    }
    __syncthreads();
    short8 afH[4], afL[4], bfH[4], bfL[4];
#pragma unroll
    for (int i=0;i<4;++i) {
      afH[i] = *(const short8*)&AsH[wm*64 + i*16 + l16][quad*8];
      afL[i] = *(const short8*)&AsL[wm*64 + i*16 + l16][quad*8];
    }
#pragma unroll
    for (int j=0;j<4;++j) {
      bfH[j] = *(const short8*)&BsH[wn*64 + j*16 + l16][quad*8];
      bfL[j] = *(const short8*)&BsL[wn*64 + j*16 + l16][quad*8];
    }
#pragma unroll
    for (int i=0;i<4;++i)
#pragma unroll
      for (int j=0;j<4;++j) {
        acc[i][j] = __builtin_amdgcn_mfma_f32_16x16x32_bf16(afH[i], bfH[j], acc[i][j], 0, 0, 0);
        acc[i][j] = __builtin_amdgcn_mfma_f32_16x16x32_bf16(afH[i], bfL[j], acc[i][j], 0, 0, 0);
        acc[i][j] = __builtin_amdgcn_mfma_f32_16x16x32_bf16(afL[i], bfH[j], acc[i][j], 0, 0, 0);
      }
    __syncthreads();
  }
#pragma unroll
  for (int i=0;i<4;++i) {
#pragma unroll
    for (int j=0;j<4;++j) {
      const int nl = n0 + wn*64 + j*16 + l16;        // col = lane&15
#pragma unroll
      for (int rg=0; rg<4; ++rg) {
        const int ml = m0 + wm*64 + i*16 + quad*4 + rg;   // row = quad*4+reg
        float val = acc[i][j][rg];
        if (nl < 256) ProjH[((size_t)b*256 + ml)*256 + nl] = (f16)val;
        else          GH[(((size_t)b*32 + (ml>>3))*768 + (nl-256))*8 + (ml&7)] = (f16)val;
      }
    }
  }
}

// ---------------- loc branch precompute (fp32): LC[b][t][i] ----------------
__global__ __launch_bounds__(256) void locpre_kernel(
    const float* __restrict__ fea, const float* __restrict__ Wlt,
    const float* __restrict__ blt, const float* __restrict__ Wlg,
    const float* __restrict__ blg, float* __restrict__ LC)
{
  const int b = blockIdx.x, tid = threadIdx.x;
  __shared__ float WT[CIN][4];
  __shared__ float S[L_][4];
  __shared__ float SW[4];
  __shared__ float BLG[4];
  for (int i = tid; i < 4*CIN; i += 256) { int ii = i >> 9, c = i & 511; WT[c][ii] = Wlg[ii*768 + 256 + c]; }
  if (tid < 4) BLG[tid] = blg[tid];
  __syncthreads();
  if (tid < 4) { float s = 0.f; for (int c = 0; c < CIN; ++c) s += WT[c][tid]; SW[tid] = s; }
  {
    const float4* fr = (const float4*)(fea + ((size_t)b*L_ + tid)*CIN);
    float a0=0.f,a1=0.f,a2=0.f,a3=0.f;
    for (int c4 = 0; c4 < CIN/4; ++c4) {
      float4 f = fr[c4]; int c = c4*4;
      a0 += f.x*WT[c][0] + f.y*WT[c+1][0] + f.z*WT[c+2][0] + f.w*WT[c+3][0];
      a1 += f.x*WT[c][1] + f.y*WT[c+1][1] + f.z*WT[c+2][1] + f.w*WT[c+3][1];
      a2 += f.x*WT[c][2] + f.y*WT[c+1][2] + f.z*WT[c+2][2] + f.w*WT[c+3][2];
      a3 += f.x*WT[c][3] + f.y*WT[c+1][3] + f.z*WT[c+2][3] + f.w*WT[c+3][3];
    }
    S[tid][0]=a0; S[tid][1]=a1; S[tid][2]=a2; S[tid][3]=a3;
  }
  __syncthreads();
  for (int t = tid; t < T_; t += 256) {
    const float* wr = Wlt + (size_t)t*L_;
    float a0=0.f,a1=0.f,a2=0.f,a3=0.f;
    for (int l = 0; l < L_; ++l) {
      float wv = wr[l];
      a0 += wv*S[l][0]; a1 += wv*S[l][1]; a2 += wv*S[l][2]; a3 += wv*S[l][3];
    }
    float bb = blt[t];
    size_t o = ((size_t)b*T_ + t)*4;
    LC[o+0] = a0 + bb*SW[0] + BLG[0];
    LC[o+1] = a1 + bb*SW[1] + BLG[1];
    LC[o+2] = a2 + bb*SW[2] + BLG[2];
    LC[o+3] = a3 + bb*SW[3] + BLG[3];
  }
}

// ---------------- persistent per-batch scan: register-resident Wrec/G/proj, 501 steps ----------------
__global__ __launch_bounds__(1024, 4) void scan_kernel(
    const uint4* __restrict__ Wrec2,           // [32 jt][1024 c] uint4 (8 halves, j=8jt..8jt+7 of col c)
    const uint4* __restrict__ G2,              // [B][32 lt][768 c] uint4 (8 halves, l=8lt..8lt+7 of col c)
    const f16*  __restrict__ Proj,             // [B][256 l][256 h]
    const uint4* __restrict__ WoutT4,          // [64 o][32] uint4 (8 halves of j)
    const float* __restrict__ WiheT,           // [30][768]
    const float* __restrict__ LC,              // [B][T][4]
    const float* __restrict__ wscore,
    const float* __restrict__ b_h2h, const float* __restrict__ b_ih,
    const float* __restrict__ b_hh,  const float* __restrict__ b_gen,
    float* __restrict__ out)
{
  const int b = blockIdx.x;
  const int tid = threadIdx.x;
  const int wv = tid >> 6, ln = tid & 63;

  __shared__ float hbuf[H_];
  __shared__ float qbuf[H_];
  __shared__ float ghb[768];
  __shared__ float gib[768];
  __shared__ float bgen_s[32];
  __shared__ float ebuf[L_];
  __shared__ float albuf[L_];
  __shared__ float red[8];
  __shared__ float p6[16][64];
  __shared__ float bc[2];
  __shared__ int elem_s;

  for (int i = tid; i < H_; i += 1024) hbuf[i] = 0.f;
  if (tid < 32) bgen_s[tid] = (tid < E_) ? b_gen[tid] : -1e30f;
  if (tid == 0) elem_s = 0;

  // ---- per-thread register-resident data (loaded once) ----
  // Wrec column c=tid: 32 uint4 = 128 VGPR
  uint4 wrc[32];
#pragma unroll
  for (int jt = 0; jt < 32; ++jt) wrc[jt] = Wrec2[(size_t)jt*1024 + tid];
  // G column c=tid (tid<768): 32 uint4 = 128 VGPR (clamped for tid>=768)
  const uint4* gpl = G2 + (size_t)b*32*768 + (tid < 768 ? tid : 0);
  uint4 grg[32];
#pragma unroll
  for (int lt = 0; lt < 32; ++lt) grg[lt] = gpl[(size_t)lt*768];
  // proj slice: l = wv*16+i, h = ln*4..ln*4+3 : 16 uint2 = 32 VGPR
  const f16* projB = Proj + (size_t)b*256*256;
  uint2 prj[16];
#pragma unroll
  for (int i = 0; i < 16; ++i) prj[i] = *(const uint2*)(projB + (size_t)(wv*16+i)*256 + ln*4);
  // w_score slice (4), Wout slice (8)
  const float4 ws4 = *(const float4*)(wscore + ln*4);
  const int o6 = tid & 63, jr = tid >> 6;
  const uint4 wo0 = WoutT4[o6*32 + jr*2];
  const uint4 wo1 = WoutT4[o6*32 + jr*2 + 1];
  // per-thread bias registers
  const float biasP1 = (tid < H_) ? b_h2h[tid] : b_hh[tid - H_];
  const float bihr   = (tid < 768) ? b_ih[tid] : 0.f;
  __syncthreads();

  float* outP = out + (size_t)b*T_*E_;
  float* outL = out + (size_t)B_*T_*E_;
  const float* lcB = LC + (size_t)b*T_*4;

  for (int t = 0; t < T_; ++t) {
    // ---- prefetch data-dependent rows (elem known from prev step; in flight through P1..P3) ----
    int elem = elem_s;
    float wie = (tid < 768) ? WiheT[(size_t)elem*768 + tid] : 0.f;
    float lcv = (tid >= 32 && tid < 36) ? lcB[(size_t)t*4 + (tid - 32)] : 0.f;

    // ---- P1: (q|gh)[c] = sum_j Wrec[j][c]*h[j], c = tid (weights in regs) ----
    {
      float acc = 0.f;
#pragma unroll
      for (int jt = 0; jt < 32; ++jt) {
        union { uint4 v; f16 h[8]; } W; W.v = wrc[jt];
        float4 ha = *(const float4*)&hbuf[jt*8];
        float4 hb = *(const float4*)&hbuf[jt*8+4];
        acc = fmam(W.h[0], ha.x, acc); acc = fmam(W.h[1], ha.y, acc);
        acc = fmam(W.h[2], ha.z, acc); acc = fmam(W.h[3], ha.w, acc);
        acc = fmam(W.h[4], hb.x, acc); acc = fmam(W.h[5], hb.y, acc);
        acc = fmam(W.h[6], hb.z, acc); acc = fmam(W.h[7], hb.w, acc);
      }
      if (tid < H_) qbuf[tid] = acc + biasP1;
      else ghb[tid - H_] = acc + biasP1;
    }
    __syncthreads();
    // ---- P2: e[l] = sum_h ws[h]*tanh(proj[l][h]+q[h]); wave per 16 l, lanes over h (proj in regs) ----
    {
      float4 q4 = *(const float4*)&qbuf[ln*4];
#pragma unroll 2
      for (int i = 0; i < 16; ++i) {
        int l = wv*16 + i;
        union { uint2 v; f16 h[4]; } P; P.v = prj[i];
        float s;
        s  = ws4.x * fast_tanh((float)P.h[0] + q4.x);
        s += ws4.y * fast_tanh((float)P.h[1] + q4.y);
        s += ws4.z * fast_tanh((float)P.h[2] + q4.z);
        s += ws4.w * fast_tanh((float)P.h[3] + q4.w);
#pragma unroll
        for (int off = 32; off >= 1; off >>= 1) s += __shfl_xor(s, off);
        if (ln == 0) ebuf[l] = s;
      }
    }
    __syncthreads();
    // ---- softmax over l (threads 0..255) ----
    {
      float ev = (tid < L_) ? ebuf[tid] : -1e30f;
      float mx = ev;
#pragma unroll
      for (int off = 32; off >= 1; off >>= 1) mx = fmaxf(mx, __shfl_xor(mx, off));
      if (tid < L_ && ln == 0) red[wv] = mx;
      __syncthreads();
      float bmax = fmaxf(fmaxf(red[0],red[1]), fmaxf(red[2],red[3]));
      float p = (tid < L_) ? __expf(ev - bmax) : 0.f;
      float sm = p;
#pragma unroll
      for (int off = 32; off >= 1; off >>= 1) sm += __shfl_xor(sm, off);
      if (tid < L_ && ln == 0) red[4 + wv] = sm;
      __syncthreads();
      float inv = 1.f / (red[4]+red[5]+red[6]+red[7]);
      if (tid < L_) albuf[tid] = p * inv;
    }
    __syncthreads();
    // ---- P4: gi[c] = sum_l G[l][c]*alpha[l] + Wihe[elem][c] + bih[c], c = tid (<768, G in regs) ----
    if (tid < 768) {
      float acc = 0.f;
#pragma unroll
      for (int lt = 0; lt < 32; ++lt) {
        union { uint4 v; f16 h[8]; } W; W.v = grg[lt];
        float4 aa = *(const float4*)&albuf[lt*8];
        float4 ab = *(const float4*)&albuf[lt*8+4];
        acc = fmam(W.h[0], aa.x, acc); acc = fmam(W.h[1], aa.y, acc);
        acc = fmam(W.h[2], aa.z, acc); acc = fmam(W.h[3], aa.w, acc);
        acc = fmam(W.h[4], ab.x, acc); acc = fmam(W.h[5], ab.y, acc);
        acc = fmam(W.h[6], ab.z, acc); acc = fmam(W.h[7], ab.w, acc);
      }
      gib[tid] = acc + wie + bihr;
    }
    __syncthreads();
    // ---- P5: GRU gates + h update ----
    if (tid < H_) {
      int h = tid;
      float r = fast_sigm(gib[h] + ghb[h]);
      float z = fast_sigm(gib[H_+h] + ghb[H_+h]);
      float n = fast_tanh(gib[2*H_+h] + r*ghb[2*H_+h]);
      hbuf[h] = (1.f - z)*n + z*hbuf[h];
    }
    __syncthreads();
    // ---- P6: output matvec partials (Wout in regs) ----
    {
      union { uint4 v; f16 h[8]; } Wa, Wb; Wa.v = wo0; Wb.v = wo1;
      const float* hb = &hbuf[jr*16];
      float4 h0 = *(const float4*)(hb);
      float4 h1 = *(const float4*)(hb+4);
      float4 h2 = *(const float4*)(hb+8);
      float4 h3 = *(const float4*)(hb+12);
      float acc = 0.f;
      acc = fmam(Wa.h[0], h0.x, acc); acc = fmam(Wa.h[1], h0.y, acc);
      acc = fmam(Wa.h[2], h0.z, acc); acc = fmam(Wa.h[3], h0.w, acc);
      acc = fmam(Wa.h[4], h1.x, acc); acc = fmam(Wa.h[5], h1.y, acc);
      acc = fmam(Wa.h[6], h1.z, acc); acc = fmam(Wa.h[7], h1.w, acc);
      acc = fmam(Wb.h[0], h2.x, acc); acc = fmam(Wb.h[1], h2.y, acc);
      acc = fmam(Wb.h[2], h2.z, acc); acc = fmam(Wb.h[3], h2.w, acc);
      acc = fmam(Wb.h[4], h3.x, acc); acc = fmam(Wb.h[5], h3.y, acc);
      acc = fmam(Wb.h[6], h3.z, acc); acc = fmam(Wb.h[7], h3.w, acc);
      p6[jr][o6] = acc;
    }
    __syncthreads();
    if (tid < 64) {
      float v = p6[0][tid];
#pragma unroll
      for (int s = 1; s < 16; ++s) v += p6[s][tid];
      p6[0][tid] = v;
    }
    __syncthreads();
    if (tid == 0) {   // first-max argmax + softmax stats
      float best = -1e30f; int bi = 0;
      float lg[E_];
      for (int m = 0; m < E_; ++m) { lg[m] = p6[0][m] + bgen_s[m]; if (lg[m] > best) { best = lg[m]; bi = m; } }
      elem_s = bi;
      float se = 0.f;
      for (int m = 0; m < E_; ++m) se += __expf(lg[m] - best);
      bc[0] = best; bc[1] = 1.f/se;
    }
    __syncthreads();
    if (tid < E_) {
      float lg = p6[0][tid] + bgen_s[tid];
      outP[(size_t)t*E_ + tid] = __expf(lg - bc[0]) * bc[1];
    } else if (tid >= 32 && tid < 36) {
      int i = tid - 32;
      outL[((size_t)b*T_ + t)*4 + i] = fast_sigm(p6[0][tid] + lcv);
    }
  }
}

extern "C" void kernel_launch(void* const* d_in, const int* in_sizes, int n_in,
                              void* d_out, int out_size, void* d_ws, size_t ws_size,
                              hipStream_t stream) {
  (void)in_sizes; (void)n_in; (void)out_size; (void)ws_size;
  const float* fea    = (const float*)d_in[0];
  const float* W_i2h  = (const float*)d_in[1];
  const float* W_h2h  = (const float*)d_in[2];
  const float* b_h2h  = (const float*)d_in[3];
  const float* wscore = (const float*)d_in[4];
  const float* W_ih   = (const float*)d_in[5];
  const float* W_hh   = (const float*)d_in[6];
  const float* b_ih   = (const float*)d_in[7];
  const float* b_hh   = (const float*)d_in[8];
  const float* W_gen  = (const float*)d_in[9];
  const float* b_gen  = (const float*)d_in[10];
  const float* Wlt    = (const float*)d_in[11];
  const float* blt    = (const float*)d_in[12];
  const float* Wlg    = (const float*)d_in[13];
  const float* blg    = (const float*)d_in[14];

  char* ws = (char*)d_ws;
  f16*            ProjH = (f16*)(ws + OFF_PROJ);
  f16*            GH    = (f16*)(ws + OFF_G);
  unsigned short* WcatH = (unsigned short*)(ws + OFF_WCTH);
  unsigned short* WcatL = (unsigned short*)(ws + OFF_WCTL);
  f16*            Wrec2 = (f16*)(ws + OFF_WREC);
  f16*            WoutT = (f16*)(ws + OFF_WOUT);
  float*          WiheT = (float*)(ws + OFF_WIHE);
  float*          LCp   = (float*)(ws + OFF_LC);

  build_weights<<<dim3(3226), dim3(256), 0, stream>>>(W_i2h, W_h2h, W_ih, W_hh, W_gen, Wlg,
                                                      WcatH, WcatL, Wrec2, WoutT, WiheT);
  gemm_kernel<<<dim3(16, B_), dim3(256), 0, stream>>>(fea, WcatH, WcatL, ProjH, GH);
  locpre_kernel<<<dim3(B_), dim3(256), 0, stream>>>(fea, Wlt, blt, Wlg, blg, LCp);
  scan_kernel<<<dim3(B_), dim3(1024), 0, stream>>>((const uint4*)Wrec2, (const uint4*)GH, ProjH,
                                                   (const uint4*)WoutT, WiheT, LCp, wscore,
                                                   b_h2h, b_ih, b_hh, b_gen, (float*)d_out);
}

// Round 5
// 35313.651 us; speedup vs baseline: 2.4802x; 2.4802x over previous
//
#include <hip/hip_runtime.h>

#define B_   128
#define L_   256
#define CIN  512
#define H_   256
#define T_   501
#define E_   30

typedef short short8 __attribute__((ext_vector_type(8)));
typedef float f32x4  __attribute__((ext_vector_type(4)));
typedef _Float16 f16;

__device__ __forceinline__ float bf2f(unsigned short s){ union{unsigned int i;float f;}v; v.i=((unsigned int)s)<<16; return v.f; }
__device__ __forceinline__ unsigned short f2bf(float f){
  union{float f;unsigned int i;}v; v.f=f;
  unsigned int x=v.i;
  return (unsigned short)((x + 0x7fffu + ((x>>16)&1u)) >> 16);
}
__device__ __forceinline__ float fast_tanh(float x){
  float t = __expf(2.f*x);
  return 1.f - 2.f*__builtin_amdgcn_rcpf(t + 1.f);
}
__device__ __forceinline__ float fast_sigm(float x){
  return __builtin_amdgcn_rcpf(1.f + __expf(-x));
}
// fp16-weight * fp32 fma with fp32 accumulate (targets v_fma_mix_f32)
__device__ __forceinline__ float fmam(f16 w, float h, float acc){ return fmaf((float)w, h, acc); }

// ---------------- workspace layout (bytes) ----------------
#define OFF_PROJ ((size_t)0)                                   // proj [B][256 l][256 h] f16 : 16,777,216
#define OFF_G    (OFF_PROJ + (size_t)B_*256*256*2)             // G [B][1536 hc][128 l'] f16 : 50,331,648
#define OFF_WCTH (OFF_G    + (size_t)B_*1536*128*2)            // WcatT_hi [1024][512] bf16 : 1,048,576
#define OFF_WCTL (OFF_WCTH + (size_t)1024*512*2)               // WcatT_lo
#define OFF_WREC (OFF_WCTL + (size_t)1024*512*2)               // Wrec2 [32 jt][1024 c][8 ji] f16 : 524,288
#define OFF_WOUT (OFF_WREC + (size_t)32*1024*8*2)              // WoutT [64 o][256 j] f16 : 32,768
#define OFF_WIHE (OFF_WOUT + (size_t)64*256*2)                 // WiheT [30][768] f32 : 92,160
#define OFF_LC   (OFF_WIHE + (size_t)30*768*4)                 // LC [B][T][4] f32 : 1,026,048

// ---------------- weight repack ----------------
__global__ __launch_bounds__(256) void build_weights(
    const float* __restrict__ W_i2h, const float* __restrict__ W_h2h,
    const float* __restrict__ W_ih,  const float* __restrict__ W_hh,
    const float* __restrict__ W_gen, const float* __restrict__ W_locgen,
    unsigned short* __restrict__ WcatT_hi, unsigned short* __restrict__ WcatT_lo,
    f16* __restrict__ Wrec2, f16* __restrict__ WoutT, float* __restrict__ WiheT)
{
  int idx = blockIdx.x*256 + threadIdx.x;
  if (idx < 524288) {                       // WcatT[n][c]: n<256 -> W_i2h row n; else W_ih row n-256 (cols 0..511)
    int n = idx >> 9, c = idx & 511;
    float v = (n < 256) ? W_i2h[n*512 + c] : W_ih[(n-256)*542 + c];
    unsigned short hi = f2bf(v);
    WcatT_hi[idx] = hi;
    WcatT_lo[idx] = f2bf(v - bf2f(hi));
    return;
  }
  idx -= 524288;
  if (idx < 262144) {                       // Wrec2[jt][col][ji] = W[col][j], j = jt*8+ji
    int ji = idx & 7, col = (idx >> 3) & 1023, jt = idx >> 13;
    int j = jt*8 + ji;
    float v = (col < 256) ? W_h2h[col*256 + j] : W_hh[(col-256)*256 + j];
    Wrec2[idx] = (f16)v; return;
  }
  idx -= 262144;
  if (idx < 16384) {                        // WoutT[o][j]: o<30 logits, o in [32,36) loc-hidden, else 0
    int o = idx >> 8, j = idx & 255;
    float v = 0.f;
    if (o < 30) v = W_gen[o*256 + j];
    else if (o >= 32 && o < 36) v = W_locgen[(o-32)*768 + j];
    WoutT[idx] = (f16)v; return;
  }
  idx -= 16384;
  if (idx < 23040) {                        // WiheT[e][k] = W_ih[k][512+e]
    int e = idx / 768, k = idx - e*768;
    WiheT[idx] = W_ih[k*542 + 512 + e];
  }
}

// ---------------- precompute GEMM, 3-pass split-bf16 (~fp32 exact): C[b] = fea[b] @ Wcat ----------------
__global__ __launch_bounds__(256) void gemm_kernel(
    const float* __restrict__ fea,
    const unsigned short* __restrict__ WcatT_hi,   // [1024][512] bf16
    const unsigned short* __restrict__ WcatT_lo,
    f16* __restrict__ ProjH,                       // [B][256][256]
    f16* __restrict__ GH)                          // [B][1536 hc][128 l']
{
  const int b = blockIdx.y;
  const int mt = blockIdx.x & 1, nt = blockIdx.x >> 1;
  const int m0 = mt*128, n0 = nt*128;
  const int tid = threadIdx.x;
  const int w = tid >> 6, lane = tid & 63;
  const int wm = w >> 1, wn = w & 1;
  const int quad = lane >> 4, l16 = lane & 15;

  __shared__ unsigned short AsH[128][40];
  __shared__ unsigned short AsL[128][40];
  __shared__ unsigned short BsH[128][40];
  __shared__ unsigned short BsL[128][40];

  f32x4 acc[4][4];
#pragma unroll
  for (int i=0;i<4;++i)
#pragma unroll
    for (int j=0;j<4;++j) acc[i][j] = (f32x4){0.f,0.f,0.f,0.f};

  const int r = tid >> 1, hf = tid & 1;

  for (int kt = 0; kt < 16; ++kt) {
    const int c0 = kt*32;
    {
      const float* src = fea + ((size_t)b*L_ + (m0+r))*CIN + c0 + hf*16;
      union { unsigned short s[8]; uint4 v; } h0, h1, l0, l1;
#pragma unroll
      for (int q4 = 0; q4 < 4; ++q4) {
        float4 f = ((const float4*)src)[q4];
        unsigned short hx = f2bf(f.x), hy = f2bf(f.y), hz = f2bf(f.z), hw = f2bf(f.w);
        unsigned short lx = f2bf(f.x - bf2f(hx)), ly = f2bf(f.y - bf2f(hy));
        unsigned short lz = f2bf(f.z - bf2f(hz)), lw = f2bf(f.w - bf2f(hw));
        if (q4 < 2) { int o = q4*4;
          h0.s[o]=hx; h0.s[o+1]=hy; h0.s[o+2]=hz; h0.s[o+3]=hw;
          l0.s[o]=lx; l0.s[o+1]=ly; l0.s[o+2]=lz; l0.s[o+3]=lw;
        } else { int o = (q4-2)*4;
          h1.s[o]=hx; h1.s[o+1]=hy; h1.s[o+2]=hz; h1.s[o+3]=hw;
          l1.s[o]=lx; l1.s[o+1]=ly; l1.s[o+2]=lz; l1.s[o+3]=lw;
        }
      }
      *(uint4*)&AsH[r][hf*16]   = h0.v;
      *(uint4*)&AsH[r][hf*16+8] = h1.v;
      *(uint4*)&AsL[r][hf*16]   = l0.v;
      *(uint4*)&AsL[r][hf*16+8] = l1.v;
      const size_t bo = ((size_t)(n0+r))*CIN + c0 + hf*16;
      uint4 bh0 = ((const uint4*)(WcatT_hi + bo))[0];
      uint4 bh1 = ((const uint4*)(WcatT_hi + bo))[1];
      uint4 bl0 = ((const uint4*)(WcatT_lo + bo))[0];
      uint4 bl1 = ((const uint4*)(WcatT_lo + bo))[1];
      *(uint4*)&BsH[r][hf*16]   = bh0;
      *(uint4*)&BsH[r][hf*16+8] = bh1;
      *(uint4*)&BsL[r][hf*16]   = bl0;
      *(uint4*)&BsL[r][hf*16+8] = bl1;
    }
    __syncthreads();
    short8 afH[4], afL[4], bfH[4], bfL[4];
#pragma unroll
    for (int i=0;i<4;++i) {
      afH[i] = *(const short8*)&AsH[wm*64 + i*16 + l16][quad*8];
      afL[i] = *(const short8*)&AsL[wm*64 + i*16 + l16][quad*8];
    }
#pragma unroll
    for (int j=0;j<4;++j) {
      bfH[j] = *(const short8*)&BsH[wn*64 + j*16 + l16][quad*8];
      bfL[j] = *(const short8*)&BsL[wn*64 + j*16 + l16][quad*8];
    }
#pragma unroll
    for (int i=0;i<4;++i)
#pragma unroll
      for (int j=0;j<4;++j) {
        acc[i][j] = __builtin_amdgcn_mfma_f32_16x16x32_bf16(afH[i], bfH[j], acc[i][j], 0, 0, 0);
        acc[i][j] = __builtin_amdgcn_mfma_f32_16x16x32_bf16(afH[i], bfL[j], acc[i][j], 0, 0, 0);
        acc[i][j] = __builtin_amdgcn_mfma_f32_16x16x32_bf16(afL[i], bfH[j], acc[i][j], 0, 0, 0);
      }
    __syncthreads();
  }
#pragma unroll
  for (int i=0;i<4;++i) {
#pragma unroll
    for (int j=0;j<4;++j) {
      const int nl = n0 + wn*64 + j*16 + l16;        // col = lane&15
#pragma unroll
      for (int rg=0; rg<4; ++rg) {
        const int ml = m0 + wm*64 + i*16 + quad*4 + rg;   // row = quad*4+reg
        float val = acc[i][j][rg];
        if (nl < 256) ProjH[((size_t)b*256 + ml)*256 + nl] = (f16)val;
        else {
          int c = nl - 256, l = ml;
          GH[((size_t)b*1536 + (size_t)(c*2 + (l>>7)))*128 + (l & 127)] = (f16)val;
        }
      }
    }
  }
}

// ---------------- loc branch precompute (fp32): LC[b][t][i] ----------------
__global__ __launch_bounds__(256) void locpre_kernel(
    const float* __restrict__ fea, const float* __restrict__ Wlt,
    const float* __restrict__ blt, const float* __restrict__ Wlg,
    const float* __restrict__ blg, float* __restrict__ LC)
{
  const int b = blockIdx.x, tid = threadIdx.x;
  __shared__ float WT[CIN][4];
  __shared__ float S[L_][4];
  __shared__ float SW[4];
  __shared__ float BLG[4];
  for (int i = tid; i < 4*CIN; i += 256) { int ii = i >> 9, c = i & 511; WT[c][ii] = Wlg[ii*768 + 256 + c]; }
  if (tid < 4) BLG[tid] = blg[tid];
  __syncthreads();
  if (tid < 4) { float s = 0.f; for (int c = 0; c < CIN; ++c) s += WT[c][tid]; SW[tid] = s; }
  {
    const float4* fr = (const float4*)(fea + ((size_t)b*L_ + tid)*CIN);
    float a0=0.f,a1=0.f,a2=0.f,a3=0.f;
    for (int c4 = 0; c4 < CIN/4; ++c4) {
      float4 f = fr[c4]; int c = c4*4;
      a0 += f.x*WT[c][0] + f.y*WT[c+1][0] + f.z*WT[c+2][0] + f.w*WT[c+3][0];
      a1 += f.x*WT[c][1] + f.y*WT[c+1][1] + f.z*WT[c+2][1] + f.w*WT[c+3][1];
      a2 += f.x*WT[c][2] + f.y*WT[c+1][2] + f.z*WT[c+2][2] + f.w*WT[c+3][2];
      a3 += f.x*WT[c][3] + f.y*WT[c+1][3] + f.z*WT[c+2][3] + f.w*WT[c+3][3];
    }
    S[tid][0]=a0; S[tid][1]=a1; S[tid][2]=a2; S[tid][3]=a3;
  }
  __syncthreads();
  for (int t = tid; t < T_; t += 256) {
    const float* wr = Wlt + (size_t)t*L_;
    float a0=0.f,a1=0.f,a2=0.f,a3=0.f;
    for (int l = 0; l < L_; ++l) {
      float wv = wr[l];
      a0 += wv*S[l][0]; a1 += wv*S[l][1]; a2 += wv*S[l][2]; a3 += wv*S[l][3];
    }
    float bb = blt[t];
    size_t o = ((size_t)b*T_ + t)*4;
    LC[o+0] = a0 + bb*SW[0] + BLG[0];
    LC[o+1] = a1 + bb*SW[1] + BLG[1];
    LC[o+2] = a2 + bb*SW[2] + BLG[2];
    LC[o+3] = a3 + bb*SW[3] + BLG[3];
  }
}

// ---------------- persistent per-batch scan: 512 threads, G in regs (192 VGPR), Wrec/proj from L2 ----------------
__global__ __launch_bounds__(512, 2) void scan_kernel(
    const uint4* __restrict__ Wrec4,           // [32 jt][1024 c] uint4 (j-rows 8jt..8jt+7 of col c)
    const uint4* __restrict__ G4,              // [B][1536 hc][16 q] uint4 (half-columns, 128 l' each)
    const f16*  __restrict__ Proj,             // [B][256 l][256 h]
    const unsigned int* __restrict__ WoutU,    // [64 o][128 jp] uint (f16 pairs over j)
    const float* __restrict__ WiheT,           // [30][768]
    const float* __restrict__ LC,              // [B][T][4]
    const float* __restrict__ wscore,
    const float* __restrict__ b_h2h, const float* __restrict__ b_ih,
    const float* __restrict__ b_hh,  const float* __restrict__ b_gen,
    float* __restrict__ out)
{
  const int b = blockIdx.x;
  const int tid = threadIdx.x;
  const int wv = tid >> 6, ln = tid & 63;

  __shared__ float hbuf[H_];
  __shared__ float qbuf[H_];
  __shared__ float ghb[768];
  __shared__ float gib[768];
  __shared__ float bih_s[768];
  __shared__ float bgen_s[32];
  __shared__ float ebuf[L_];
  __shared__ float albuf[L_];
  __shared__ float red[8];
  __shared__ float p4buf[1536];
  __shared__ float p6[8][64];
  __shared__ float bc[2];
  __shared__ unsigned int WoutLDS[8192];   // [128 jp][64 o]
  __shared__ int elem_s;

  for (int i = tid; i < H_; i += 512) hbuf[i] = 0.f;
  for (int i = tid; i < 768; i += 512) bih_s[i] = b_ih[i];
  if (tid < 32) bgen_s[tid] = (tid < E_) ? b_gen[tid] : -1e30f;
  if (tid == 0) elem_s = 0;
  for (int i = tid; i < 8192; i += 512) {
    int jp = i >> 6, o = i & 63;
    WoutLDS[i] = WoutU[o*128 + jp];
  }

  // ---- G register-resident: thread holds half-cols hc = 3tid..3tid+2 (48 uint4 = 192 VGPR) ----
  uint4 grg[48];
  {
    const uint4* gsrc = G4 + ((size_t)b*1536 + (size_t)tid*3)*16;
#pragma unroll
    for (int k = 0; k < 48; ++k) grg[k] = gsrc[k];
  }
  const float4 ws4 = *(const float4*)(wscore + ln*4);
  const float biasA = (tid < 256) ? b_h2h[tid] : b_hh[tid - 256];
  const float biasB = b_hh[tid + 256];
  __syncthreads();

  const f16* projB = Proj + (size_t)b*256*256;
  float* outP = out + (size_t)b*T_*E_;
  float* outL = out + (size_t)B_*T_*E_;
  const float* lcB = LC + (size_t)b*T_*4;

  for (int t = 0; t < T_; ++t) {
    // data-dependent prefetches (elem stable since last argmax barrier)
    int elem = elem_s;
    float wieA = WiheT[(size_t)elem*768 + tid];
    float wieB = (tid < 256) ? WiheT[(size_t)elem*768 + 512 + tid] : 0.f;
    float lcv = (tid >= 32 && tid < 36) ? lcB[(size_t)t*4 + (tid - 32)] : 0.f;

    // ---- P1: (q|gh)[c] for c = tid and c = tid+512 (Wrec streamed from L2) ----
    {
      float accA = 0.f, accB = 0.f;
      const uint4* wp = Wrec4 + tid;
#pragma unroll 4
      for (int jt = 0; jt < 32; ++jt) {
        uint4 uA = wp[jt*1024];
        uint4 uB = wp[jt*1024 + 512];
        float4 ha = *(const float4*)&hbuf[jt*8];
        float4 hb2 = *(const float4*)&hbuf[jt*8+4];
        union { uint4 v; f16 h[8]; } WA, WB; WA.v = uA; WB.v = uB;
        accA = fmam(WA.h[0], ha.x, accA); accA = fmam(WA.h[1], ha.y, accA);
        accA = fmam(WA.h[2], ha.z, accA); accA = fmam(WA.h[3], ha.w, accA);
        accA = fmam(WA.h[4], hb2.x, accA); accA = fmam(WA.h[5], hb2.y, accA);
        accA = fmam(WA.h[6], hb2.z, accA); accA = fmam(WA.h[7], hb2.w, accA);
        accB = fmam(WB.h[0], ha.x, accB); accB = fmam(WB.h[1], ha.y, accB);
        accB = fmam(WB.h[2], ha.z, accB); accB = fmam(WB.h[3], ha.w, accB);
        accB = fmam(WB.h[4], hb2.x, accB); accB = fmam(WB.h[5], hb2.y, accB);
        accB = fmam(WB.h[6], hb2.z, accB); accB = fmam(WB.h[7], hb2.w, accB);
      }
      if (tid < 256) qbuf[tid] = accA + biasA; else ghb[tid - 256] = accA + biasA;
      ghb[tid + 256] = accB + biasB;
    }
    __syncthreads();
    // ---- P2: e[l] = sum_h ws[h]*tanh(proj[l][h]+q[h]); wave per 32 l, lanes over h (proj from L2) ----
    {
      float4 q4 = *(const float4*)&qbuf[ln*4];
      int l0 = wv*32;
#pragma unroll 4
      for (int i = 0; i < 32; ++i) {
        int l = l0 + i;
        union { uint2 v; f16 h[4]; } P;
        P.v = *(const uint2*)(projB + (size_t)l*256 + ln*4);
        float s;
        s  = ws4.x * fast_tanh((float)P.h[0] + q4.x);
        s += ws4.y * fast_tanh((float)P.h[1] + q4.y);
        s += ws4.z * fast_tanh((float)P.h[2] + q4.z);
        s += ws4.w * fast_tanh((float)P.h[3] + q4.w);
#pragma unroll
        for (int off = 32; off >= 1; off >>= 1) s += __shfl_xor(s, off);
        if (ln == 0) ebuf[l] = s;
      }
    }
    __syncthreads();
    // ---- P3: softmax over l (threads 0..255) ----
    {
      float ev = (tid < L_) ? ebuf[tid] : -1e30f;
      float mx = ev;
#pragma unroll
      for (int off = 32; off >= 1; off >>= 1) mx = fmaxf(mx, __shfl_xor(mx, off));
      if (tid < L_ && ln == 0) red[wv] = mx;
      __syncthreads();
      float bmax = fmaxf(fmaxf(red[0],red[1]), fmaxf(red[2],red[3]));
      float p = (tid < L_) ? __expf(ev - bmax) : 0.f;
      float sm = p;
#pragma unroll
      for (int off = 32; off >= 1; off >>= 1) sm += __shfl_xor(sm, off);
      if (tid < L_ && ln == 0) red[4 + wv] = sm;
      __syncthreads();
      float inv = 1.f / (red[4]+red[5]+red[6]+red[7]);
      if (tid < L_) albuf[tid] = p * inv;
    }
    __syncthreads();
    // ---- P4a: half-column partials from register-resident G ----
    {
#pragma unroll
      for (int k3 = 0; k3 < 3; ++k3) {
        int hc = tid*3 + k3;
        const float* ab = &albuf[(hc & 1) * 128];
        float part = 0.f;
#pragma unroll
        for (int q = 0; q < 16; ++q) {
          union { uint4 v; f16 h[8]; } W; W.v = grg[k3*16 + q];
          float4 a0 = *(const float4*)&ab[q*8];
          float4 a1 = *(const float4*)&ab[q*8+4];
          part = fmam(W.h[0], a0.x, part); part = fmam(W.h[1], a0.y, part);
          part = fmam(W.h[2], a0.z, part); part = fmam(W.h[3], a0.w, part);
          part = fmam(W.h[4], a1.x, part); part = fmam(W.h[5], a1.y, part);
          part = fmam(W.h[6], a1.z, part); part = fmam(W.h[7], a1.w, part);
        }
        p4buf[hc] = part;
      }
    }
    __syncthreads();
    // ---- P4b: combine halves + one-hot column + bias ----
    {
      int cA = tid;
      gib[cA] = p4buf[2*cA] + p4buf[2*cA+1] + wieA + bih_s[cA];
      if (tid < 256) {
        int cB = 512 + tid;
        gib[cB] = p4buf[2*cB] + p4buf[2*cB+1] + wieB + bih_s[cB];
      }
    }
    __syncthreads();
    // ---- P5: GRU gates + h update ----
    if (tid < H_) {
      int h = tid;
      float r = fast_sigm(gib[h] + ghb[h]);
      float z = fast_sigm(gib[H_+h] + ghb[H_+h]);
      float n = fast_tanh(gib[2*H_+h] + r*ghb[2*H_+h]);
      hbuf[h] = (1.f - z)*n + z*hbuf[h];
    }
    __syncthreads();
    // ---- P6: output matvec partials (Wout in LDS); wave wv covers j in [wv*32, wv*32+32) ----
    {
      const float* hb = hbuf + wv*32;
      float acc = 0.f;
#pragma unroll
      for (int jp = 0; jp < 16; ++jp) {
        union { unsigned int v; f16 h[2]; } W; W.v = WoutLDS[(wv*16 + jp)*64 + ln];
        float2 hp = *(const float2*)&hb[jp*2];
        acc = fmam(W.h[0], hp.x, acc);
        acc = fmam(W.h[1], hp.y, acc);
      }
      p6[wv][ln] = acc;
    }
    __syncthreads();
    if (tid < 64) {
      float v = p6[0][tid];
#pragma unroll
      for (int s = 1; s < 8; ++s) v += p6[s][tid];
      p6[0][tid] = v;
    }
    __syncthreads();
    if (tid == 0) {   // first-max argmax + softmax stats
      float best = -1e30f; int bi = 0;
      float lg[E_];
      for (int m = 0; m < E_; ++m) { lg[m] = p6[0][m] + bgen_s[m]; if (lg[m] > best) { best = lg[m]; bi = m; } }
      elem_s = bi;
      float se = 0.f;
      for (int m = 0; m < E_; ++m) se += __expf(lg[m] - best);
      bc[0] = best; bc[1] = 1.f/se;
    }
    __syncthreads();
    if (tid < E_) {
      float lg = p6[0][tid] + bgen_s[tid];
      outP[(size_t)t*E_ + tid] = __expf(lg - bc[0]) * bc[1];
    } else if (tid >= 32 && tid < 36) {
      int i = tid - 32;
      outL[((size_t)b*T_ + t)*4 + i] = fast_sigm(p6[0][tid] + lcv);
    }
  }
}

extern "C" void kernel_launch(void* const* d_in, const int* in_sizes, int n_in,
                              void* d_out, int out_size, void* d_ws, size_t ws_size,
                              hipStream_t stream) {
  (void)in_sizes; (void)n_in; (void)out_size; (void)ws_size;
  const float* fea    = (const float*)d_in[0];
  const float* W_i2h  = (const float*)d_in[1];
  const float* W_h2h  = (const float*)d_in[2];
  const float* b_h2h  = (const float*)d_in[3];
  const float* wscore = (const float*)d_in[4];
  const float* W_ih   = (const float*)d_in[5];
  const float* W_hh   = (const float*)d_in[6];
  const float* b_ih   = (const float*)d_in[7];
  const float* b_hh   = (const float*)d_in[8];
  const float* W_gen  = (const float*)d_in[9];
  const float* b_gen  = (const float*)d_in[10];
  const float* Wlt    = (const float*)d_in[11];
  const float* blt    = (const float*)d_in[12];
  const float* Wlg    = (const float*)d_in[13];
  const float* blg    = (const float*)d_in[14];

  char* ws = (char*)d_ws;
  f16*            ProjH = (f16*)(ws + OFF_PROJ);
  f16*            GH    = (f16*)(ws + OFF_G);
  unsigned short* WcatH = (unsigned short*)(ws + OFF_WCTH);
  unsigned short* WcatL = (unsigned short*)(ws + OFF_WCTL);
  f16*            Wrec2 = (f16*)(ws + OFF_WREC);
  f16*            WoutT = (f16*)(ws + OFF_WOUT);
  float*          WiheT = (float*)(ws + OFF_WIHE);
  float*          LCp   = (float*)(ws + OFF_LC);

  build_weights<<<dim3(3226), dim3(256), 0, stream>>>(W_i2h, W_h2h, W_ih, W_hh, W_gen, Wlg,
                                                      WcatH, WcatL, Wrec2, WoutT, WiheT);
  gemm_kernel<<<dim3(16, B_), dim3(256), 0, stream>>>(fea, WcatH, WcatL, ProjH, GH);
  locpre_kernel<<<dim3(B_), dim3(256), 0, stream>>>(fea, Wlt, blt, Wlg, blg, LCp);
  scan_kernel<<<dim3(B_), dim3(512), 0, stream>>>((const uint4*)Wrec2, (const uint4*)GH, ProjH,
                                                  (const unsigned int*)WoutT, WiheT, LCp, wscore,
                                                  b_h2h, b_ih, b_hh, b_gen, (float*)d_out);
}

// Round 6
// 27256.021 us; speedup vs baseline: 3.2134x; 1.2956x over previous
//
#include <hip/hip_runtime.h>

#define B_   128
#define L_   256
#define CIN  512
#define H_   256
#define T_   501
#define E_   30

typedef short short8 __attribute__((ext_vector_type(8)));
typedef float f32x4  __attribute__((ext_vector_type(4)));
typedef _Float16 f16;

__device__ __forceinline__ float bf2f(unsigned short s){ union{unsigned int i;float f;}v; v.i=((unsigned int)s)<<16; return v.f; }
__device__ __forceinline__ unsigned short f2bf(float f){
  union{float f;unsigned int i;}v; v.f=f;
  unsigned int x=v.i;
  return (unsigned short)((x + 0x7fffu + ((x>>16)&1u)) >> 16);
}
__device__ __forceinline__ float fast_tanh(float x){
  float t = __expf(2.f*x);
  return 1.f - 2.f*__builtin_amdgcn_rcpf(t + 1.f);
}
__device__ __forceinline__ float fast_sigm(float x){
  return __builtin_amdgcn_rcpf(1.f + __expf(-x));
}
// fp16-weight * fp32 fma with fp32 accumulate (targets v_fma_mix_f32)
__device__ __forceinline__ float fmam(f16 w, float h, float acc){ return fmaf((float)w, h, acc); }

// ---------------- workspace layout (bytes) ----------------
#define OFF_PROJ ((size_t)0)                                   // proj [B][256 l][256 h] f16 : 16,777,216
#define OFF_G    (OFF_PROJ + (size_t)B_*256*256*2)             // G [B][3072 qc][64 l'] f16 : 50,331,648
#define OFF_WCTH (OFF_G    + (size_t)B_*3072*64*2)             // WcatT_hi [1024][512] bf16 : 1,048,576
#define OFF_WCTL (OFF_WCTH + (size_t)1024*512*2)               // WcatT_lo
#define OFF_WREC (OFF_WCTL + (size_t)1024*512*2)               // Wrec2 [32 jt][1024 c][8 ji] f16 : 524,288
#define OFF_WOUT (OFF_WREC + (size_t)32*1024*8*2)              // WoutT [64 o][256 j] f16 : 32,768
#define OFF_WIHE (OFF_WOUT + (size_t)64*256*2)                 // WiheT [30][768] f32 : 92,160
#define OFF_LC   (OFF_WIHE + (size_t)30*768*4)                 // LC [B][T][4] f32 : 1,026,048

// ---------------- weight repack ----------------
__global__ __launch_bounds__(256) void build_weights(
    const float* __restrict__ W_i2h, const float* __restrict__ W_h2h,
    const float* __restrict__ W_ih,  const float* __restrict__ W_hh,
    const float* __restrict__ W_gen, const float* __restrict__ W_locgen,
    unsigned short* __restrict__ WcatT_hi, unsigned short* __restrict__ WcatT_lo,
    f16* __restrict__ Wrec2, f16* __restrict__ WoutT, float* __restrict__ WiheT)
{
  int idx = blockIdx.x*256 + threadIdx.x;
  if (idx < 524288) {                       // WcatT[n][c]: n<256 -> W_i2h row n; else W_ih row n-256 (cols 0..511)
    int n = idx >> 9, c = idx & 511;
    float v = (n < 256) ? W_i2h[n*512 + c] : W_ih[(n-256)*542 + c];
    unsigned short hi = f2bf(v);
    WcatT_hi[idx] = hi;
    WcatT_lo[idx] = f2bf(v - bf2f(hi));
    return;
  }
  idx -= 524288;
  if (idx < 262144) {                       // Wrec2[jt][col][ji] = W[col][j], j = jt*8+ji
    int ji = idx & 7, col = (idx >> 3) & 1023, jt = idx >> 13;
    int j = jt*8 + ji;
    float v = (col < 256) ? W_h2h[col*256 + j] : W_hh[(col-256)*256 + j];
    Wrec2[idx] = (f16)v; return;
  }
  idx -= 262144;
  if (idx < 16384) {                        // WoutT[o][j]: o<30 logits, o in [32,36) loc-hidden, else 0
    int o = idx >> 8, j = idx & 255;
    float v = 0.f;
    if (o < 30) v = W_gen[o*256 + j];
    else if (o >= 32 && o < 36) v = W_locgen[(o-32)*768 + j];
    WoutT[idx] = (f16)v; return;
  }
  idx -= 16384;
  if (idx < 23040) {                        // WiheT[e][k] = W_ih[k][512+e]
    int e = idx / 768, k = idx - e*768;
    WiheT[idx] = W_ih[k*542 + 512 + e];
  }
}

// ---------------- precompute GEMM, 3-pass split-bf16 (~fp32 exact): C[b] = fea[b] @ Wcat ----------------
__global__ __launch_bounds__(256) void gemm_kernel(
    const float* __restrict__ fea,
    const unsigned short* __restrict__ WcatT_hi,   // [1024][512] bf16
    const unsigned short* __restrict__ WcatT_lo,
    f16* __restrict__ ProjH,                       // [B][256][256]
    f16* __restrict__ GH)                          // [B][3072 qc][64 l'] ; qc = c*4 + (l>>6)
{
  const int b = blockIdx.y;
  const int mt = blockIdx.x & 1, nt = blockIdx.x >> 1;
  const int m0 = mt*128, n0 = nt*128;
  const int tid = threadIdx.x;
  const int w = tid >> 6, lane = tid & 63;
  const int wm = w >> 1, wn = w & 1;
  const int quad = lane >> 4, l16 = lane & 15;

  __shared__ unsigned short AsH[128][40];
  __shared__ unsigned short AsL[128][40];
  __shared__ unsigned short BsH[128][40];
  __shared__ unsigned short BsL[128][40];

  f32x4 acc[4][4];
#pragma unroll
  for (int i=0;i<4;++i)
#pragma unroll
    for (int j=0;j<4;++j) acc[i][j] = (f32x4){0.f,0.f,0.f,0.f};

  const int r = tid >> 1, hf = tid & 1;

  for (int kt = 0; kt < 16; ++kt) {
    const int c0 = kt*32;
    {
      const float* src = fea + ((size_t)b*L_ + (m0+r))*CIN + c0 + hf*16;
      union { unsigned short s[8]; uint4 v; } h0, h1, l0, l1;
#pragma unroll
      for (int q4 = 0; q4 < 4; ++q4) {
        float4 f = ((const float4*)src)[q4];
        unsigned short hx = f2bf(f.x), hy = f2bf(f.y), hz = f2bf(f.z), hw = f2bf(f.w);
        unsigned short lx = f2bf(f.x - bf2f(hx)), ly = f2bf(f.y - bf2f(hy));
        unsigned short lz = f2bf(f.z - bf2f(hz)), lw = f2bf(f.w - bf2f(hw));
        if (q4 < 2) { int o = q4*4;
          h0.s[o]=hx; h0.s[o+1]=hy; h0.s[o+2]=hz; h0.s[o+3]=hw;
          l0.s[o]=lx; l0.s[o+1]=ly; l0.s[o+2]=lz; l0.s[o+3]=lw;
        } else { int o = (q4-2)*4;
          h1.s[o]=hx; h1.s[o+1]=hy; h1.s[o+2]=hz; h1.s[o+3]=hw;
          l1.s[o]=lx; l1.s[o+1]=ly; l1.s[o+2]=lz; l1.s[o+3]=lw;
        }
      }
      *(uint4*)&AsH[r][hf*16]   = h0.v;
      *(uint4*)&AsH[r][hf*16+8] = h1.v;
      *(uint4*)&AsL[r][hf*16]   = l0.v;
      *(uint4*)&AsL[r][hf*16+8] = l1.v;
      const size_t bo = ((size_t)(n0+r))*CIN + c0 + hf*16;
      uint4 bh0 = ((const uint4*)(WcatT_hi + bo))[0];
      uint4 bh1 = ((const uint4*)(WcatT_hi + bo))[1];
      uint4 bl0 = ((const uint4*)(WcatT_lo + bo))[0];
      uint4 bl1 = ((const uint4*)(WcatT_lo + bo))[1];
      *(uint4*)&BsH[r][hf*16]   = bh0;
      *(uint4*)&BsH[r][hf*16+8] = bh1;
      *(uint4*)&BsL[r][hf*16]   = bl0;
      *(uint4*)&BsL[r][hf*16+8] = bl1;
    }
    __syncthreads();
    short8 afH[4], afL[4], bfH[4], bfL[4];
#pragma unroll
    for (int i=0;i<4;++i) {
      afH[i] = *(const short8*)&AsH[wm*64 + i*16 + l16][quad*8];
      afL[i] = *(const short8*)&AsL[wm*64 + i*16 + l16][quad*8];
    }
#pragma unroll
    for (int j=0;j<4;++j) {
      bfH[j] = *(const short8*)&BsH[wn*64 + j*16 + l16][quad*8];
      bfL[j] = *(const short8*)&BsL[wn*64 + j*16 + l16][quad*8];
    }
#pragma unroll
    for (int i=0;i<4;++i)
#pragma unroll
      for (int j=0;j<4;++j) {
        acc[i][j] = __builtin_amdgcn_mfma_f32_16x16x32_bf16(afH[i], bfH[j], acc[i][j], 0, 0, 0);
        acc[i][j] = __builtin_amdgcn_mfma_f32_16x16x32_bf16(afH[i], bfL[j], acc[i][j], 0, 0, 0);
        acc[i][j] = __builtin_amdgcn_mfma_f32_16x16x32_bf16(afL[i], bfH[j], acc[i][j], 0, 0, 0);
      }
    __syncthreads();
  }
#pragma unroll
  for (int i=0;i<4;++i) {
#pragma unroll
    for (int j=0;j<4;++j) {
      const int nl = n0 + wn*64 + j*16 + l16;        // col = lane&15
#pragma unroll
      for (int rg=0; rg<4; ++rg) {
        const int ml = m0 + wm*64 + i*16 + quad*4 + rg;   // row = quad*4+reg
        float val = acc[i][j][rg];
        if (nl < 256) ProjH[((size_t)b*256 + ml)*256 + nl] = (f16)val;
        else {
          int c = nl - 256, l = ml;
          GH[((size_t)b*3072 + (size_t)(c*4 + (l>>6)))*64 + (l & 63)] = (f16)val;
        }
      }
    }
  }
}

// ---------------- loc branch precompute (fp32): LC[b][t][i] ----------------
__global__ __launch_bounds__(256) void locpre_kernel(
    const float* __restrict__ fea, const float* __restrict__ Wlt,
    const float* __restrict__ blt, const float* __restrict__ Wlg,
    const float* __restrict__ blg, float* __restrict__ LC)
{
  const int b = blockIdx.x, tid = threadIdx.x;
  __shared__ float WT[CIN][4];
  __shared__ float S[L_][4];
  __shared__ float SW[4];
  __shared__ float BLG[4];
  for (int i = tid; i < 4*CIN; i += 256) { int ii = i >> 9, c = i & 511; WT[c][ii] = Wlg[ii*768 + 256 + c]; }
  if (tid < 4) BLG[tid] = blg[tid];
  __syncthreads();
  if (tid < 4) { float s = 0.f; for (int c = 0; c < CIN; ++c) s += WT[c][tid]; SW[tid] = s; }
  {
    const float4* fr = (const float4*)(fea + ((size_t)b*L_ + tid)*CIN);
    float a0=0.f,a1=0.f,a2=0.f,a3=0.f;
    for (int c4 = 0; c4 < CIN/4; ++c4) {
      float4 f = fr[c4]; int c = c4*4;
      a0 += f.x*WT[c][0] + f.y*WT[c+1][0] + f.z*WT[c+2][0] + f.w*WT[c+3][0];
      a1 += f.x*WT[c][1] + f.y*WT[c+1][1] + f.z*WT[c+2][1] + f.w*WT[c+3][1];
      a2 += f.x*WT[c][2] + f.y*WT[c+1][2] + f.z*WT[c+2][2] + f.w*WT[c+3][2];
      a3 += f.x*WT[c][3] + f.y*WT[c+1][3] + f.z*WT[c+2][3] + f.w*WT[c+3][3];
    }
    S[tid][0]=a0; S[tid][1]=a1; S[tid][2]=a2; S[tid][3]=a3;
  }
  __syncthreads();
  for (int t = tid; t < T_; t += 256) {
    const float* wr = Wlt + (size_t)t*L_;
    float a0=0.f,a1=0.f,a2=0.f,a3=0.f;
    for (int l = 0; l < L_; ++l) {
      float wv = wr[l];
      a0 += wv*S[l][0]; a1 += wv*S[l][1]; a2 += wv*S[l][2]; a3 += wv*S[l][3];
    }
    float bb = blt[t];
    size_t o = ((size_t)b*T_ + t)*4;
    LC[o+0] = a0 + bb*SW[0] + BLG[0];
    LC[o+1] = a1 + bb*SW[1] + BLG[1];
    LC[o+2] = a2 + bb*SW[2] + BLG[2];
    LC[o+3] = a3 + bb*SW[3] + BLG[3];
  }
}

// ---------------- persistent per-batch scan: 1024 thr, G reg-resident (96 VGPR), Wrec/proj from L2 ----------------
__global__ __launch_bounds__(1024) void scan_kernel(
    const uint4* __restrict__ Wrec4,           // [32 jt][1024 c] uint4 (j-rows 8jt..8jt+7 of col c)
    const uint4* __restrict__ G4,              // [B][3072 qc][8] uint4 (quarter-cols: 64 l' each)
    const f16*  __restrict__ Proj,             // [B][256 l][256 h]
    const unsigned int* __restrict__ WoutU,    // [64 o][128 jp] uint (f16 pairs over j)
    const float* __restrict__ WiheT,           // [30][768]
    const float* __restrict__ LC,              // [B][T][4]
    const float* __restrict__ wscore,
    const float* __restrict__ b_h2h, const float* __restrict__ b_ih,
    const float* __restrict__ b_hh,  const float* __restrict__ b_gen,
    float* __restrict__ out)
{
  const int b = blockIdx.x;
  const int tid = threadIdx.x;
  const int wv = tid >> 6, ln = tid & 63;

  __shared__ float hbuf[H_];
  __shared__ float qbuf[H_];
  __shared__ float ghb[768];
  __shared__ float gib[768];
  __shared__ float bgen_s[32];
  __shared__ float ebuf[L_];
  __shared__ float albuf[L_];
  __shared__ float red[8];
  __shared__ float p4buf[3072];
  __shared__ float p6[16][64];
  __shared__ float bc[2];
  __shared__ unsigned int WoutLDS[8192];   // [128 jp][64 o]
  __shared__ int elem_s;

  for (int i = tid; i < H_; i += 1024) hbuf[i] = 0.f;
  if (tid < 32) bgen_s[tid] = (tid < E_) ? b_gen[tid] : -1e30f;
  if (tid == 0) elem_s = 0;
  for (int i = tid; i < 8192; i += 1024) {
    int jp = i >> 6, o = i & 63;
    WoutLDS[i] = WoutU[o*128 + jp];
  }

  // ---- G register-resident: thread holds quarter-cols qc = 3tid..3tid+2 (24 uint4 = 96 VGPR) ----
  uint4 grg[24];
  {
    const uint4* gsrc = G4 + ((size_t)b*3072 + (size_t)tid*3)*8;
#pragma unroll
    for (int k = 0; k < 24; ++k) grg[k] = gsrc[k];
  }
  const float4 ws4 = *(const float4*)(wscore + ln*4);
  const float biasP1 = (tid < H_) ? b_h2h[tid] : b_hh[tid - H_];
  const float bihr   = (tid < 768) ? b_ih[tid] : 0.f;
  __syncthreads();

  const f16* projB = Proj + (size_t)b*256*256;
  float* outP = out + (size_t)b*T_*E_;
  float* outL = out + (size_t)B_*T_*E_;
  const float* lcB = LC + (size_t)b*T_*4;

  for (int t = 0; t < T_; ++t) {
    // data-dependent prefetches (elem stable since last argmax barrier)
    int elem = elem_s;
    float wie = (tid < 768) ? WiheT[(size_t)elem*768 + tid] : 0.f;
    float lcv = (tid >= 32 && tid < 36) ? lcB[(size_t)t*4 + (tid - 32)] : 0.f;

    // ---- P1: (q|gh)[c] = sum_j Wrec[j][c]*h[j], c = tid (Wrec streamed from L2) ----
    {
      float acc = 0.f;
      const uint4* wp = Wrec4 + tid;
#pragma unroll 4
      for (int jt = 0; jt < 32; ++jt) {
        uint4 u = wp[jt*1024];
        union { uint4 v; f16 h[8]; } W; W.v = u;
        float4 ha = *(const float4*)&hbuf[jt*8];
        float4 hb = *(const float4*)&hbuf[jt*8+4];
        acc = fmam(W.h[0], ha.x, acc); acc = fmam(W.h[1], ha.y, acc);
        acc = fmam(W.h[2], ha.z, acc); acc = fmam(W.h[3], ha.w, acc);
        acc = fmam(W.h[4], hb.x, acc); acc = fmam(W.h[5], hb.y, acc);
        acc = fmam(W.h[6], hb.z, acc); acc = fmam(W.h[7], hb.w, acc);
      }
      if (tid < H_) qbuf[tid] = acc + biasP1;
      else ghb[tid - H_] = acc + biasP1;
    }
    __syncthreads();
    // ---- P2: e[l] = sum_h ws[h]*tanh(proj[l][h]+q[h]); wave per 16 l, lanes over h (proj from L2) ----
    {
      float4 q4 = *(const float4*)&qbuf[ln*4];
#pragma unroll 2
      for (int i = 0; i < 16; ++i) {
        int l = wv*16 + i;
        union { uint2 v; f16 h[4]; } P;
        P.v = *(const uint2*)(projB + (size_t)l*256 + ln*4);
        float s;
        s  = ws4.x * fast_tanh((float)P.h[0] + q4.x);
        s += ws4.y * fast_tanh((float)P.h[1] + q4.y);
        s += ws4.z * fast_tanh((float)P.h[2] + q4.z);
        s += ws4.w * fast_tanh((float)P.h[3] + q4.w);
#pragma unroll
        for (int off = 32; off >= 1; off >>= 1) s += __shfl_xor(s, off);
        if (ln == 0) ebuf[l] = s;
      }
    }
    __syncthreads();
    // ---- P3: softmax over l (threads 0..255) ----
    {
      float ev = (tid < L_) ? ebuf[tid] : -1e30f;
      float mx = ev;
#pragma unroll
      for (int off = 32; off >= 1; off >>= 1) mx = fmaxf(mx, __shfl_xor(mx, off));
      if (tid < L_ && ln == 0) red[wv] = mx;
      __syncthreads();
      float bmax = fmaxf(fmaxf(red[0],red[1]), fmaxf(red[2],red[3]));
      float p = (tid < L_) ? __expf(ev - bmax) : 0.f;
      float sm = p;
#pragma unroll
      for (int off = 32; off >= 1; off >>= 1) sm += __shfl_xor(sm, off);
      if (tid < L_ && ln == 0) red[4 + wv] = sm;
      __syncthreads();
      float inv = 1.f / (red[4]+red[5]+red[6]+red[7]);
      if (tid < L_) albuf[tid] = p * inv;
    }
    __syncthreads();
    // ---- P4a: quarter-column partials from register-resident G ----
    {
#pragma unroll
      for (int k3 = 0; k3 < 3; ++k3) {
        int qc = tid*3 + k3;
        const float* ab = &albuf[(qc & 3) * 64];
        float part = 0.f;
#pragma unroll
        for (int q = 0; q < 8; ++q) {
          union { uint4 v; f16 h[8]; } W; W.v = grg[k3*8 + q];
          float4 a0 = *(const float4*)&ab[q*8];
          float4 a1 = *(const float4*)&ab[q*8+4];
          part = fmam(W.h[0], a0.x, part); part = fmam(W.h[1], a0.y, part);
          part = fmam(W.h[2], a0.z, part); part = fmam(W.h[3], a0.w, part);
          part = fmam(W.h[4], a1.x, part); part = fmam(W.h[5], a1.y, part);
          part = fmam(W.h[6], a1.z, part); part = fmam(W.h[7], a1.w, part);
        }
        p4buf[qc] = part;
      }
    }
    __syncthreads();
    // ---- P4b: combine quarters + one-hot column + bias ----
    if (tid < 768) {
      float4 pq = *(const float4*)&p4buf[4*tid];
      gib[tid] = (pq.x + pq.y) + (pq.z + pq.w) + wie + bihr;
    }
    __syncthreads();
    // ---- P5: GRU gates + h update ----
    if (tid < H_) {
      int h = tid;
      float r = fast_sigm(gib[h] + ghb[h]);
      float z = fast_sigm(gib[H_+h] + ghb[H_+h]);
      float n = fast_tanh(gib[2*H_+h] + r*ghb[2*H_+h]);
      hbuf[h] = (1.f - z)*n + z*hbuf[h];
    }
    __syncthreads();
    // ---- P6: output matvec partials (Wout in LDS); thread (jr,o6): j in [jr*16, jr*16+16) ----
    {
      const int o6 = tid & 63, jr = tid >> 6;
      float acc = 0.f;
#pragma unroll
      for (int p = 0; p < 8; ++p) {
        int jp = jr*8 + p;
        union { unsigned int v; f16 h[2]; } W; W.v = WoutLDS[jp*64 + o6];
        float2 hp = *(const float2*)&hbuf[jp*2];
        acc = fmam(W.h[0], hp.x, acc);
        acc = fmam(W.h[1], hp.y, acc);
      }
      p6[jr][o6] = acc;
    }
    __syncthreads();
    if (tid < 64) {
      float v = p6[0][tid];
#pragma unroll
      for (int s = 1; s < 16; ++s) v += p6[s][tid];
      p6[0][tid] = v;
    }
    __syncthreads();
    if (tid == 0) {   // first-max argmax + softmax stats
      float best = -1e30f; int bi = 0;
      float lg[E_];
      for (int m = 0; m < E_; ++m) { lg[m] = p6[0][m] + bgen_s[m]; if (lg[m] > best) { best = lg[m]; bi = m; } }
      elem_s = bi;
      float se = 0.f;
      for (int m = 0; m < E_; ++m) se += __expf(lg[m] - best);
      bc[0] = best; bc[1] = 1.f/se;
    }
    __syncthreads();
    if (tid < E_) {
      float lg = p6[0][tid] + bgen_s[tid];
      outP[(size_t)t*E_ + tid] = __expf(lg - bc[0]) * bc[1];
    } else if (tid >= 32 && tid < 36) {
      int i = tid - 32;
      outL[((size_t)b*T_ + t)*4 + i] = fast_sigm(p6[0][tid] + lcv);
    }
  }
}

extern "C" void kernel_launch(void* const* d_in, const int* in_sizes, int n_in,
                              void* d_out, int out_size, void* d_ws, size_t ws_size,
                              hipStream_t stream) {
  (void)in_sizes; (void)n_in; (void)out_size; (void)ws_size;
  const float* fea    = (const float*)d_in[0];
  const float* W_i2h  = (const float*)d_in[1];
  const float* W_h2h  = (const float*)d_in[2];
  const float* b_h2h  = (const float*)d_in[3];
  const float* wscore = (const float*)d_in[4];
  const float* W_ih   = (const float*)d_in[5];
  const float* W_hh   = (const float*)d_in[6];
  const float* b_ih   = (const float*)d_in[7];
  const float* b_hh   = (const float*)d_in[8];
  const float* W_gen  = (const float*)d_in[9];
  const float* b_gen  = (const float*)d_in[10];
  const float* Wlt    = (const float*)d_in[11];
  const float* blt    = (const float*)d_in[12];
  const float* Wlg    = (const float*)d_in[13];
  const float* blg    = (const float*)d_in[14];

  char* ws = (char*)d_ws;
  f16*            ProjH = (f16*)(ws + OFF_PROJ);
  f16*            GH    = (f16*)(ws + OFF_G);
  unsigned short* WcatH = (unsigned short*)(ws + OFF_WCTH);
  unsigned short* WcatL = (unsigned short*)(ws + OFF_WCTL);
  f16*            Wrec2 = (f16*)(ws + OFF_WREC);
  f16*            WoutT = (f16*)(ws + OFF_WOUT);
  float*          WiheT = (float*)(ws + OFF_WIHE);
  float*          LCp   = (float*)(ws + OFF_LC);

  build_weights<<<dim3(3226), dim3(256), 0, stream>>>(W_i2h, W_h2h, W_ih, W_hh, W_gen, Wlg,
                                                      WcatH, WcatL, Wrec2, WoutT, WiheT);
  gemm_kernel<<<dim3(16, B_), dim3(256), 0, stream>>>(fea, WcatH, WcatL, ProjH, GH);
  locpre_kernel<<<dim3(B_), dim3(256), 0, stream>>>(fea, Wlt, blt, Wlg, blg, LCp);
  scan_kernel<<<dim3(B_), dim3(1024), 0, stream>>>((const uint4*)Wrec2, (const uint4*)GH, ProjH,
                                                   (const unsigned int*)WoutT, WiheT, LCp, wscore,
                                                   b_h2h, b_ih, b_hh, b_gen, (float*)d_out);
}

// Round 7
// 14430.782 us; speedup vs baseline: 6.0694x; 1.8887x over previous
//
#include <hip/hip_runtime.h>

#define B_   128
#define L_   256
#define CIN  512
#define H_   256
#define T_   501
#define E_   30

typedef short short8 __attribute__((ext_vector_type(8)));
typedef float f32x4  __attribute__((ext_vector_type(4)));
typedef _Float16 f16;

__device__ __forceinline__ float bf2f(unsigned short s){ union{unsigned int i;float f;}v; v.i=((unsigned int)s)<<16; return v.f; }
__device__ __forceinline__ unsigned short f2bf(float f){
  union{float f;unsigned int i;}v; v.f=f;
  unsigned int x=v.i;
  return (unsigned short)((x + 0x7fffu + ((x>>16)&1u)) >> 16);
}
__device__ __forceinline__ float fast_tanh(float x){
  float t = __expf(2.f*x);
  return 1.f - 2.f*__builtin_amdgcn_rcpf(t + 1.f);
}
__device__ __forceinline__ float fast_sigm(float x){
  return __builtin_amdgcn_rcpf(1.f + __expf(-x));
}
__device__ __forceinline__ float fmam(f16 w, float h, float acc){ return fmaf((float)w, h, acc); }

// ---------------- workspace layout (bytes) ----------------
#define OFF_PROJ ((size_t)0)                                   // proj [B][256 l][256 h] f16 : 16,777,216
#define OFF_GA   (OFF_PROJ + (size_t)B_*256*256*2)             // GA [B][2 lh][128 ls][512 c] f16 : 33,554,432 (LDS-hosted part)
#define OFF_GB   (OFF_GA   + (size_t)B_*2*128*512*2)           // GB [B][2 lh][16 q][256 c][8] f16 : 16,777,216 (streamed part)
#define OFF_WCTH (OFF_GB   + (size_t)B_*2*16*256*8*2)          // WcatT_hi [1024][512] bf16
#define OFF_WCTL (OFF_WCTH + (size_t)1024*512*2)
#define OFF_WREC (OFF_WCTL + (size_t)1024*512*2)               // Wrec2 [32 jt][1024 c][8 ji] f16
#define OFF_WOUT (OFF_WREC + (size_t)32*1024*8*2)              // WoutT [64 o][256 j] f16
#define OFF_WIHE (OFF_WOUT + (size_t)64*256*2)                 // WiheT [30][768] f32
#define OFF_LC   (OFF_WIHE + (size_t)30*768*4)                 // LC [B][T][4] f32 : 1,026,048
#define OFF_MBQ  (OFF_LC   + (size_t)B_*T_*4*4)                // mbQ [B][1024] f32 : 524,288
#define OFF_MBG  (OFF_MBQ  + (size_t)B_*1024*4)                // mbG [B][2][768] f32 : 786,432
#define OFF_FLG  (OFF_MBG  + (size_t)B_*2*768*4)               // flags [B][2 half][2 s] int : 2048

// ---------------- weight repack ----------------
__global__ __launch_bounds__(256) void build_weights(
    const float* __restrict__ W_i2h, const float* __restrict__ W_h2h,
    const float* __restrict__ W_ih,  const float* __restrict__ W_hh,
    const float* __restrict__ W_gen, const float* __restrict__ W_locgen,
    unsigned short* __restrict__ WcatT_hi, unsigned short* __restrict__ WcatT_lo,
    f16* __restrict__ Wrec2, f16* __restrict__ WoutT, float* __restrict__ WiheT)
{
  int idx = blockIdx.x*256 + threadIdx.x;
  if (idx < 524288) {                       // WcatT[n][c]: n<256 -> W_i2h row n; else W_ih row n-256 (cols 0..511)
    int n = idx >> 9, c = idx & 511;
    float v = (n < 256) ? W_i2h[n*512 + c] : W_ih[(n-256)*542 + c];
    unsigned short hi = f2bf(v);
    WcatT_hi[idx] = hi;
    WcatT_lo[idx] = f2bf(v - bf2f(hi));
    return;
  }
  idx -= 524288;
  if (idx < 262144) {                       // Wrec2[jt][col][ji] = W[col][j], j = jt*8+ji
    int ji = idx & 7, col = (idx >> 3) & 1023, jt = idx >> 13;
    int j = jt*8 + ji;
    float v = (col < 256) ? W_h2h[col*256 + j] : W_hh[(col-256)*256 + j];
    Wrec2[idx] = (f16)v; return;
  }
  idx -= 262144;
  if (idx < 16384) {                        // WoutT[o][j]
    int o = idx >> 8, j = idx & 255;
    float v = 0.f;
    if (o < 30) v = W_gen[o*256 + j];
    else if (o >= 32 && o < 36) v = W_locgen[(o-32)*768 + j];
    WoutT[idx] = (f16)v; return;
  }
  idx -= 16384;
  if (idx < 23040) {                        // WiheT[e][k] = W_ih[k][512+e]
    int e = idx / 768, k = idx - e*768;
    WiheT[idx] = W_ih[k*542 + 512 + e];
  }
}

// ---------------- precompute GEMM, 3-pass split-bf16 (~fp32 exact) ----------------
__global__ __launch_bounds__(256) void gemm_kernel(
    const float* __restrict__ fea,
    const unsigned short* __restrict__ WcatT_hi,
    const unsigned short* __restrict__ WcatT_lo,
    f16* __restrict__ ProjH,                       // [B][256][256]
    f16* __restrict__ GA,                          // [B][2][128][512]
    f16* __restrict__ GB)                          // [B][2][16][256][8]
{
  const int b = blockIdx.y;
  const int mt = blockIdx.x & 1, nt = blockIdx.x >> 1;
  const int m0 = mt*128, n0 = nt*128;
  const int tid = threadIdx.x;
  const int w = tid >> 6, lane = tid & 63;
  const int wm = w >> 1, wn = w & 1;
  const int quad = lane >> 4, l16 = lane & 15;

  __shared__ unsigned short AsH[128][40];
  __shared__ unsigned short AsL[128][40];
  __shared__ unsigned short BsH[128][40];
  __shared__ unsigned short BsL[128][40];

  f32x4 acc[4][4];
#pragma unroll
  for (int i=0;i<4;++i)
#pragma unroll
    for (int j=0;j<4;++j) acc[i][j] = (f32x4){0.f,0.f,0.f,0.f};

  const int r = tid >> 1, hf = tid & 1;

  for (int kt = 0; kt < 16; ++kt) {
    const int c0 = kt*32;
    {
      const float* src = fea + ((size_t)b*L_ + (m0+r))*CIN + c0 + hf*16;
      union { unsigned short s[8]; uint4 v; } h0, h1, l0, l1;
#pragma unroll
      for (int q4 = 0; q4 < 4; ++q4) {
        float4 f = ((const float4*)src)[q4];
        unsigned short hx = f2bf(f.x), hy = f2bf(f.y), hz = f2bf(f.z), hw = f2bf(f.w);
        unsigned short lx = f2bf(f.x - bf2f(hx)), ly = f2bf(f.y - bf2f(hy));
        unsigned short lz = f2bf(f.z - bf2f(hz)), lw = f2bf(f.w - bf2f(hw));
        if (q4 < 2) { int o = q4*4;
          h0.s[o]=hx; h0.s[o+1]=hy; h0.s[o+2]=hz; h0.s[o+3]=hw;
          l0.s[o]=lx; l0.s[o+1]=ly; l0.s[o+2]=lz; l0.s[o+3]=lw;
        } else { int o = (q4-2)*4;
          h1.s[o]=hx; h1.s[o+1]=hy; h1.s[o+2]=hz; h1.s[o+3]=hw;
          l1.s[o]=lx; l1.s[o+1]=ly; l1.s[o+2]=lz; l1.s[o+3]=lw;
        }
      }
      *(uint4*)&AsH[r][hf*16]   = h0.v;
      *(uint4*)&AsH[r][hf*16+8] = h1.v;
      *(uint4*)&AsL[r][hf*16]   = l0.v;
      *(uint4*)&AsL[r][hf*16+8] = l1.v;
      const size_t bo = ((size_t)(n0+r))*CIN + c0 + hf*16;
      uint4 bh0 = ((const uint4*)(WcatT_hi + bo))[0];
      uint4 bh1 = ((const uint4*)(WcatT_hi + bo))[1];
      uint4 bl0 = ((const uint4*)(WcatT_lo + bo))[0];
      uint4 bl1 = ((const uint4*)(WcatT_lo + bo))[1];
      *(uint4*)&BsH[r][hf*16]   = bh0;
      *(uint4*)&BsH[r][hf*16+8] = bh1;
      *(uint4*)&BsL[r][hf*16]   = bl0;
      *(uint4*)&BsL[r][hf*16+8] = bl1;
    }
    __syncthreads();
    short8 afH[4], afL[4], bfH[4], bfL[4];
#pragma unroll
    for (int i=0;i<4;++i) {
      afH[i] = *(const short8*)&AsH[wm*64 + i*16 + l16][quad*8];
      afL[i] = *(const short8*)&AsL[wm*64 + i*16 + l16][quad*8];
    }
#pragma unroll
    for (int j=0;j<4;++j) {
      bfH[j] = *(const short8*)&BsH[wn*64 + j*16 + l16][quad*8];
      bfL[j] = *(const short8*)&BsL[wn*64 + j*16 + l16][quad*8];
    }
#pragma unroll
    for (int i=0;i<4;++i)
#pragma unroll
      for (int j=0;j<4;++j) {
        acc[i][j] = __builtin_amdgcn_mfma_f32_16x16x32_bf16(afH[i], bfH[j], acc[i][j], 0, 0, 0);
        acc[i][j] = __builtin_amdgcn_mfma_f32_16x16x32_bf16(afH[i], bfL[j], acc[i][j], 0, 0, 0);
        acc[i][j] = __builtin_amdgcn_mfma_f32_16x16x32_bf16(afL[i], bfH[j], acc[i][j], 0, 0, 0);
      }
    __syncthreads();
  }
#pragma unroll
  for (int i=0;i<4;++i) {
#pragma unroll
    for (int j=0;j<4;++j) {
      const int nl = n0 + wn*64 + j*16 + l16;
#pragma unroll
      for (int rg=0; rg<4; ++rg) {
        const int ml = m0 + wm*64 + i*16 + quad*4 + rg;
        float val = acc[i][j][rg];
        if (nl < 256) ProjH[((size_t)b*256 + ml)*256 + nl] = (f16)val;
        else {
          int c = nl - 256, l = ml, lh = l >> 7, ls = l & 127;
          if (c < 512) GA[(((size_t)b*2 + lh)*128 + ls)*512 + c] = (f16)val;
          else GB[((((size_t)b*2 + lh)*16 + (ls>>3))*256 + (c-512))*8 + (ls&7)] = (f16)val;
        }
      }
    }
  }
}

// ---------------- loc branch precompute (fp32) ----------------
__global__ __launch_bounds__(256) void locpre_kernel(
    const float* __restrict__ fea, const float* __restrict__ Wlt,
    const float* __restrict__ blt, const float* __restrict__ Wlg,
    const float* __restrict__ blg, float* __restrict__ LC)
{
  const int b = blockIdx.x, tid = threadIdx.x;
  __shared__ float WT[CIN][4];
  __shared__ float S[L_][4];
  __shared__ float SW[4];
  __shared__ float BLG[4];
  for (int i = tid; i < 4*CIN; i += 256) { int ii = i >> 9, c = i & 511; WT[c][ii] = Wlg[ii*768 + 256 + c]; }
  if (tid < 4) BLG[tid] = blg[tid];
  __syncthreads();
  if (tid < 4) { float s = 0.f; for (int c = 0; c < CIN; ++c) s += WT[c][tid]; SW[tid] = s; }
  {
    const float4* fr = (const float4*)(fea + ((size_t)b*L_ + tid)*CIN);
    float a0=0.f,a1=0.f,a2=0.f,a3=0.f;
    for (int c4 = 0; c4 < CIN/4; ++c4) {
      float4 f = fr[c4]; int c = c4*4;
      a0 += f.x*WT[c][0] + f.y*WT[c+1][0] + f.z*WT[c+2][0] + f.w*WT[c+3][0];
      a1 += f.x*WT[c][1] + f.y*WT[c+1][1] + f.z*WT[c+2][1] + f.w*WT[c+3][1];
      a2 += f.x*WT[c][2] + f.y*WT[c+1][2] + f.z*WT[c+2][2] + f.w*WT[c+3][2];
      a3 += f.x*WT[c][3] + f.y*WT[c+1][3] + f.z*WT[c+2][3] + f.w*WT[c+3][3];
    }
    S[tid][0]=a0; S[tid][1]=a1; S[tid][2]=a2; S[tid][3]=a3;
  }
  __syncthreads();
  for (int t = tid; t < T_; t += 256) {
    const float* wr = Wlt + (size_t)t*L_;
    float a0=0.f,a1=0.f,a2=0.f,a3=0.f;
    for (int l = 0; l < L_; ++l) {
      float wv = wr[l];
      a0 += wv*S[l][0]; a1 += wv*S[l][1]; a2 += wv*S[l][2]; a3 += wv*S[l][3];
    }
    float bb = blt[t];
    size_t o = ((size_t)b*T_ + t)*4;
    LC[o+0] = a0 + bb*SW[0] + BLG[0];
    LC[o+1] = a1 + bb*SW[1] + BLG[1];
    LC[o+2] = a2 + bb*SW[2] + BLG[2];
    LC[o+3] = a3 + bb*SW[3] + BLG[3];
  }
}

// ---------------- pair-split scan: 256 blocks (2 per batch), G l-half in dynamic LDS ----------------
__global__ __launch_bounds__(1024) void scan_kernel(
    const uint4* __restrict__ Wrec4,           // [32 jt][1024 c] uint4
    const f16*  __restrict__ GA,               // [B][2][128 ls][512 c]
    const uint4* __restrict__ GB4,             // [B][2][16 q][256 c] uint4
    const f16*  __restrict__ Proj,             // [B][256 l][256 h]
    const uint4* __restrict__ WoutT4,          // [64 o][32] uint4
    const float* __restrict__ WiheT,           // [30][768]
    const float* __restrict__ LC,              // [B][T][4]
    const float* __restrict__ wscore,
    const float* __restrict__ b_h2h, const float* __restrict__ b_ih,
    const float* __restrict__ b_hh,  const float* __restrict__ b_gen,
    float* __restrict__ mbQ,                   // [B][1024]
    float* __restrict__ mbG,                   // [B][2][768]
    int*   __restrict__ flags,                 // [B][2][2]
    float* __restrict__ out)
{
  const int bid = blockIdx.x;
  const int b = bid & 127, half = bid >> 7;
  const int tid = threadIdx.x;
  const int wv = tid >> 6, ln = tid & 63;

  extern __shared__ char dynls[];
  f16* Gl = (f16*)dynls;                       // [128 ls][512 c] = 128 KB

  __shared__ float hbuf[H_];
  __shared__ float qbuf[H_];
  __shared__ float ghb[768];
  __shared__ float gib[768];
  __shared__ float bgen_s[32];
  __shared__ float ebuf[L_];
  __shared__ float albuf[L_];
  __shared__ float red[8];
  __shared__ float p1buf[1024];
  __shared__ float p4buf[768];
  __shared__ float p6[16][64];
  __shared__ float bc[2];
  __shared__ int elem_s;

  for (int i = tid; i < H_; i += 1024) hbuf[i] = 0.f;
  if (tid < 32) bgen_s[tid] = (tid < E_) ? b_gen[tid] : -1e30f;
  if (tid == 0) elem_s = 0;

  // load LDS-hosted G l-half once (128 KB, coalesced)
  {
    const uint4* gsrc = (const uint4*)(GA + (size_t)(b*2 + half)*128*512);
    uint4* gdst = (uint4*)Gl;
    for (int i = tid; i < 8192; i += 1024) gdst[i] = gsrc[i];
  }
  // per-thread invariants
  const float4 ws4 = *(const float4*)(wscore + ln*4);
  const int o6 = tid & 63, jr = tid >> 6;
  const uint4 wo0 = WoutT4[o6*32 + jr*2];
  const uint4 wo1 = WoutT4[o6*32 + jr*2 + 1];
  const int myc = half*512 + (tid & 511);       // P1 column for combine stage (tid<512)
  const float biasC = (tid < 512) ? ((myc < 256) ? b_h2h[myc] : b_hh[myc - 256]) : 0.f;
  const float bihr  = (tid < 768) ? b_ih[tid] : 0.f;
  __syncthreads();

  const f16* projB = Proj + (size_t)b*256*256;
  const unsigned int* GlU = (const unsigned int*)Gl;   // [128][256] uint (2 cols each)
  float* mbQb = mbQ + (size_t)b*1024;
  float* mbGme = mbG + ((size_t)b*2 + half)*768;
  float* mbGpa = mbG + ((size_t)b*2 + (1-half))*768;
  int* flg = flags + (size_t)b*4;
  const int fS1me = half*2, fS2me = half*2+1, fS1pa = (1-half)*2, fS2pa = (1-half)*2+1;
  float* outP = out + (size_t)b*T_*E_;
  float* outL = out + (size_t)B_*T_*E_;
  const float* lcB = LC + (size_t)b*T_*4;

  for (int t = 0; t < T_; ++t) {
    int elem = elem_s;
    float wie = (tid < 768) ? WiheT[(size_t)elem*768 + tid] : 0.f;
    float lcv = (half == 0 && tid >= 32 && tid < 36) ? lcB[(size_t)t*4 + (tid - 32)] : 0.f;

    // ---- P1 (split): block computes cols half*512 .. half*512+511; 2 threads per col (j-halves) ----
    {
      const int cl = tid & 511, jb = tid >> 9;
      float acc = 0.f;
      const uint4* wp = Wrec4 + (half*512 + cl) + (size_t)jb*16*1024;
#pragma unroll 4
      for (int jt = 0; jt < 16; ++jt) {
        uint4 u = wp[(size_t)jt*1024];
        union { uint4 v; f16 h[8]; } W; W.v = u;
        const int j0 = (jb*16 + jt)*8;
        float4 ha = *(const float4*)&hbuf[j0];
        float4 hb = *(const float4*)&hbuf[j0+4];
        acc = fmam(W.h[0], ha.x, acc); acc = fmam(W.h[1], ha.y, acc);
        acc = fmam(W.h[2], ha.z, acc); acc = fmam(W.h[3], ha.w, acc);
        acc = fmam(W.h[4], hb.x, acc); acc = fmam(W.h[5], hb.y, acc);
        acc = fmam(W.h[6], hb.z, acc); acc = fmam(W.h[7], hb.w, acc);
      }
      p1buf[tid] = acc;
    }
    __syncthreads();
    if (tid < 512) {
      float v = p1buf[tid] + p1buf[512 + tid] + biasC;
      if (myc < 256) qbuf[myc] = v; else ghb[myc - 256] = v;
      __hip_atomic_store(&mbQb[myc], v, __ATOMIC_RELAXED, __HIP_MEMORY_SCOPE_AGENT);
    }
    __syncthreads();            // all mbQ stores drained (barrier waits vmcnt)
    // ---- S1: exchange (q|gh) halves ----
    if (tid == 0) {
      __hip_atomic_store(&flg[fS1me], t+1, __ATOMIC_RELEASE, __HIP_MEMORY_SCOPE_AGENT);
      while (__hip_atomic_load(&flg[fS1pa], __ATOMIC_ACQUIRE, __HIP_MEMORY_SCOPE_AGENT) < t+1)
        __builtin_amdgcn_s_sleep(2);
    }
    __syncthreads();
    if (tid < 512) {
      int pc = (1-half)*512 + tid;
      float v = __hip_atomic_load(&mbQb[pc], __ATOMIC_RELAXED, __HIP_MEMORY_SCOPE_AGENT);
      if (pc < 256) qbuf[pc] = v; else ghb[pc - 256] = v;
    }
    __syncthreads();
    // ---- P2 (redundant, full): e[l] = sum_h ws[h]*tanh(proj[l][h]+q[h]) ----
    {
      float4 q4 = *(const float4*)&qbuf[ln*4];
#pragma unroll 2
      for (int i = 0; i < 16; ++i) {
        int l = wv*16 + i;
        union { uint2 v; f16 h[4]; } P;
        P.v = *(const uint2*)(projB + (size_t)l*256 + ln*4);
        float s;
        s  = ws4.x * fast_tanh((float)P.h[0] + q4.x);
        s += ws4.y * fast_tanh((float)P.h[1] + q4.y);
        s += ws4.z * fast_tanh((float)P.h[2] + q4.z);
        s += ws4.w * fast_tanh((float)P.h[3] + q4.w);
#pragma unroll
        for (int off = 32; off >= 1; off >>= 1) s += __shfl_xor(s, off);
        if (ln == 0) ebuf[l] = s;
      }
    }
    __syncthreads();
    // ---- P3 (redundant): softmax over l ----
    {
      float ev = (tid < L_) ? ebuf[tid] : -1e30f;
      float mx = ev;
#pragma unroll
      for (int off = 32; off >= 1; off >>= 1) mx = fmaxf(mx, __shfl_xor(mx, off));
      if (tid < L_ && ln == 0) red[wv] = mx;
      __syncthreads();
      float bmax = fmaxf(fmaxf(red[0],red[1]), fmaxf(red[2],red[3]));
      float p = (tid < L_) ? __expf(ev - bmax) : 0.f;
      float sm = p;
#pragma unroll
      for (int off = 32; off >= 1; off >>= 1) sm += __shfl_xor(sm, off);
      if (tid < L_ && ln == 0) red[4 + wv] = sm;
      __syncthreads();
      float inv = 1.f / (red[4]+red[5]+red[6]+red[7]);
      if (tid < L_) albuf[tid] = p * inv;
    }
    __syncthreads();
    // ---- P4a (split by l-half): partial gi over this block's 128 l ----
    if (tid < 256) {
      // LDS-hosted cols 0..511: thread t handles cols 2t, 2t+1
      float a0 = 0.f, a1 = 0.f;
      const float* ab = &albuf[half*128];
#pragma unroll 8
      for (int l = 0; l < 128; ++l) {
        unsigned int u = GlU[l*256 + tid];
        union { unsigned int v; f16 h[2]; } W; W.v = u;
        float al = ab[l];
        a0 = fmam(W.h[0], al, a0);
        a1 = fmam(W.h[1], al, a1);
      }
      p4buf[2*tid] = a0; p4buf[2*tid+1] = a1;
    } else if (tid < 512) {
      // streamed cols 512..767: thread 256+k handles col 512+k
      const int k = tid - 256;
      const uint4* gp = GB4 + (size_t)(b*2 + half)*16*256 + k;
      float acc = 0.f;
#pragma unroll 4
      for (int q = 0; q < 16; ++q) {
        uint4 u = gp[(size_t)q*256];
        union { uint4 v; f16 h[8]; } W; W.v = u;
        float4 aa = *(const float4*)&albuf[half*128 + q*8];
        float4 ab2 = *(const float4*)&albuf[half*128 + q*8 + 4];
        acc = fmam(W.h[0], aa.x, acc); acc = fmam(W.h[1], aa.y, acc);
        acc = fmam(W.h[2], aa.z, acc); acc = fmam(W.h[3], aa.w, acc);
        acc = fmam(W.h[4], ab2.x, acc); acc = fmam(W.h[5], ab2.y, acc);
        acc = fmam(W.h[6], ab2.z, acc); acc = fmam(W.h[7], ab2.w, acc);
      }
      p4buf[512 + k] = acc;
    }
    __syncthreads();
    if (tid < 768)
      __hip_atomic_store(&mbGme[tid], p4buf[tid], __ATOMIC_RELAXED, __HIP_MEMORY_SCOPE_AGENT);
    __syncthreads();
    // ---- S2: exchange gi partials ----
    if (tid == 0) {
      __hip_atomic_store(&flg[fS2me], t+1, __ATOMIC_RELEASE, __HIP_MEMORY_SCOPE_AGENT);
      while (__hip_atomic_load(&flg[fS2pa], __ATOMIC_ACQUIRE, __HIP_MEMORY_SCOPE_AGENT) < t+1)
        __builtin_amdgcn_s_sleep(2);
    }
    __syncthreads();
    if (tid < 768) {
      float theirs = __hip_atomic_load(&mbGpa[tid], __ATOMIC_RELAXED, __HIP_MEMORY_SCOPE_AGENT);
      float mine = p4buf[tid];
      float g0 = (half == 0) ? mine : theirs;
      float g1 = (half == 0) ? theirs : mine;
      gib[tid] = ((g0 + g1) + wie) + bihr;
    }
    __syncthreads();
    // ---- P5 (redundant): GRU gates + h update ----
    if (tid < H_) {
      int h = tid;
      float r = fast_sigm(gib[h] + ghb[h]);
      float z = fast_sigm(gib[H_+h] + ghb[H_+h]);
      float n = fast_tanh(gib[2*H_+h] + r*ghb[2*H_+h]);
      hbuf[h] = (1.f - z)*n + z*hbuf[h];
    }
    __syncthreads();
    // ---- P6 (redundant): output matvec, argmax, outputs ----
    {
      union { uint4 v; f16 h[8]; } Wa, Wb; Wa.v = wo0; Wb.v = wo1;
      const float* hb = &hbuf[jr*16];
      float4 h0 = *(const float4*)(hb);
      float4 h1 = *(const float4*)(hb+4);
      float4 h2 = *(const float4*)(hb+8);
      float4 h3 = *(const float4*)(hb+12);
      float acc = 0.f;
      acc = fmam(Wa.h[0], h0.x, acc); acc = fmam(Wa.h[1], h0.y, acc);
      acc = fmam(Wa.h[2], h0.z, acc); acc = fmam(Wa.h[3], h0.w, acc);
      acc = fmam(Wa.h[4], h1.x, acc); acc = fmam(Wa.h[5], h1.y, acc);
      acc = fmam(Wa.h[6], h1.z, acc); acc = fmam(Wa.h[7], h1.w, acc);
      acc = fmam(Wb.h[0], h2.x, acc); acc = fmam(Wb.h[1], h2.y, acc);
      acc = fmam(Wb.h[2], h2.z, acc); acc = fmam(Wb.h[3], h2.w, acc);
      acc = fmam(Wb.h[4], h3.x, acc); acc = fmam(Wb.h[5], h3.y, acc);
      acc = fmam(Wb.h[6], h3.z, acc); acc = fmam(Wb.h[7], h3.w, acc);
      p6[jr][o6] = acc;
    }
    __syncthreads();
    if (tid < 64) {
      float v = p6[0][tid];
#pragma unroll
      for (int s = 1; s < 16; ++s) v += p6[s][tid];
      p6[0][tid] = v;
    }
    __syncthreads();
    if (tid == 0) {
      float best = -1e30f; int bi = 0;
      float lg[E_];
      for (int m = 0; m < E_; ++m) { lg[m] = p6[0][m] + bgen_s[m]; if (lg[m] > best) { best = lg[m]; bi = m; } }
      elem_s = bi;
      float se = 0.f;
      for (int m = 0; m < E_; ++m) se += __expf(lg[m] - best);
      bc[0] = best; bc[1] = 1.f/se;
    }
    __syncthreads();
    if (half == 0) {
      if (tid < E_) {
        float lg = p6[0][tid] + bgen_s[tid];
        outP[(size_t)t*E_ + tid] = __expf(lg - bc[0]) * bc[1];
      } else if (tid >= 32 && tid < 36) {
        int i = tid - 32;
        outL[((size_t)b*T_ + t)*4 + i] = fast_sigm(p6[0][tid] + lcv);
      }
    }
  }
}

extern "C" void kernel_launch(void* const* d_in, const int* in_sizes, int n_in,
                              void* d_out, int out_size, void* d_ws, size_t ws_size,
                              hipStream_t stream) {
  (void)in_sizes; (void)n_in; (void)out_size; (void)ws_size;
  const float* fea    = (const float*)d_in[0];
  const float* W_i2h  = (const float*)d_in[1];
  const float* W_h2h  = (const float*)d_in[2];
  const float* b_h2h  = (const float*)d_in[3];
  const float* wscore = (const float*)d_in[4];
  const float* W_ih   = (const float*)d_in[5];
  const float* W_hh   = (const float*)d_in[6];
  const float* b_ih   = (const float*)d_in[7];
  const float* b_hh   = (const float*)d_in[8];
  const float* W_gen  = (const float*)d_in[9];
  const float* b_gen  = (const float*)d_in[10];
  const float* Wlt    = (const float*)d_in[11];
  const float* blt    = (const float*)d_in[12];
  const float* Wlg    = (const float*)d_in[13];
  const float* blg    = (const float*)d_in[14];

  char* ws = (char*)d_ws;
  f16*            ProjH = (f16*)(ws + OFF_PROJ);
  f16*            GA    = (f16*)(ws + OFF_GA);
  f16*            GB    = (f16*)(ws + OFF_GB);
  unsigned short* WcatH = (unsigned short*)(ws + OFF_WCTH);
  unsigned short* WcatL = (unsigned short*)(ws + OFF_WCTL);
  f16*            Wrec2 = (f16*)(ws + OFF_WREC);
  f16*            WoutT = (f16*)(ws + OFF_WOUT);
  float*          WiheT = (float*)(ws + OFF_WIHE);
  float*          LCp   = (float*)(ws + OFF_LC);
  float*          mbQ   = (float*)(ws + OFF_MBQ);
  float*          mbG   = (float*)(ws + OFF_MBG);
  int*            flg   = (int*)(ws + OFF_FLG);

  static bool attr_set = false;
  (void)attr_set;
  hipFuncSetAttribute((const void*)scan_kernel,
                      hipFuncAttributeMaxDynamicSharedMemorySize, 131072);

  build_weights<<<dim3(3226), dim3(256), 0, stream>>>(W_i2h, W_h2h, W_ih, W_hh, W_gen, Wlg,
                                                      WcatH, WcatL, Wrec2, WoutT, WiheT);
  gemm_kernel<<<dim3(16, B_), dim3(256), 0, stream>>>(fea, WcatH, WcatL, ProjH, GA, GB);
  locpre_kernel<<<dim3(B_), dim3(256), 0, stream>>>(fea, Wlt, blt, Wlg, blg, LCp);
  scan_kernel<<<dim3(256), dim3(1024), 131072, stream>>>((const uint4*)Wrec2, GA, (const uint4*)GB,
                                                         ProjH, (const uint4*)WoutT, WiheT, LCp, wscore,
                                                         b_h2h, b_ih, b_hh, b_gen,
                                                         mbQ, mbG, flg, (float*)d_out);
}